// Round 7
// baseline (410.874 us; speedup 1.0000x reference)
//
#include <hip/hip_runtime.h>
#include <stdint.h>

typedef unsigned short u16;
typedef __attribute__((ext_vector_type(8))) short s16x8;
typedef __attribute__((ext_vector_type(4))) float f32x4;

#define B_   2
#define T_   2048
#define DM   2048
#define H_   16
#define HD_  128
#define R_   64
#define E_   192
// 1/sqrt(192) * log2(e): softmax in base-2 domain
#define SCALE2 0.104117542f

__device__ __forceinline__ u16 f2b(float f) {
  union { float f; uint32_t u; } x; x.f = f;
  uint32_t u = x.u;
  return (u16)((u + 0x7FFFu + ((u >> 16) & 1u)) >> 16);  // RNE
}
__device__ __forceinline__ float b2f(u16 h) {
  union { uint32_t u; float f; } x; x.u = ((uint32_t)h) << 16;
  return x.f;
}
// pack two f32 -> two bf16 (truncation; used only for P which is renormalized by row-sum)
__device__ __forceinline__ unsigned pk2(float a, float b) {
  union { float f; unsigned u; } A, B; A.f = a; B.f = b;
  return (B.u & 0xFFFF0000u) | (A.u >> 16);
}
// async global->LDS, 16B/lane; LDS dest = wave-uniform base + lane*16
__device__ __forceinline__ void ld_lds16(const void* g, void* l) {
  __builtin_amdgcn_global_load_lds((const __attribute__((address_space(1))) void*)g,
                                   (__attribute__((address_space(3))) void*)l,
                                   16, 0, 0);
}

// ---------- device helpers: conv + 64x64 transpose tile ----------
__device__ __forceinline__ void conv_dev(const float* __restrict__ in, u16* __restrict__ out, int i) {
  float4 v = *(const float4*)(in + (size_t)i * 4);
  ushort4 o;
  o.x = f2b(v.x); o.y = f2b(v.y); o.z = f2b(v.z); o.w = f2b(v.w);
  *(ushort4*)(out + (size_t)i * 4) = o;
}
__device__ __forceinline__ void tr64(const float* __restrict__ in, u16* __restrict__ out,
                                     int K, int N, int bx, int by) {
  __shared__ u16 t[64][65];
  int bn = bx * 64, bk = by * 64;
  int tid = threadIdx.x;
  int r0 = tid >> 4, c0 = (tid & 15) * 4;
#pragma unroll
  for (int rr = 0; rr < 64; rr += 16) {
    float4 v = *(const float4*)(in + (size_t)(bk + r0 + rr) * N + bn + c0);
    t[r0 + rr][c0 + 0] = f2b(v.x); t[r0 + rr][c0 + 1] = f2b(v.y);
    t[r0 + rr][c0 + 2] = f2b(v.z); t[r0 + rr][c0 + 3] = f2b(v.w);
  }
  __syncthreads();
#pragma unroll
  for (int rr = 0; rr < 64; rr += 16) {
    ushort4 v;
    v.x = t[c0 + 0][r0 + rr]; v.y = t[c0 + 1][r0 + rr];
    v.z = t[c0 + 2][r0 + rr]; v.w = t[c0 + 3][r0 + rr];
    *(ushort4*)(out + (size_t)(bn + r0 + rr) * K + bk + c0) = v;
  }
}

// ---------- TA: conv x, conv fr, transpose {W_DKV, W_KR, W_DQ} into gx arena ----------
__global__ __launch_bounds__(256)
void ta_k(const float* __restrict__ x, const float* __restrict__ fr,
          u16* __restrict__ x_bf, u16* __restrict__ fr_bf,
          const float* __restrict__ wdkv, const float* __restrict__ wkr,
          const float* __restrict__ wdq, u16* __restrict__ W) {
  int id = blockIdx.x;
  if (id < 8192)        conv_dev(x, x_bf, id * 256 + threadIdx.x);
  else if (id < 8256)   conv_dev(fr, fr_bf, (id - 8192) * 256 + threadIdx.x);
  else if (id < 8512) { int i = id - 8256; tr64(wdkv, W, 2048, 512, i & 7, i >> 3); }
  else if (id < 8544) { int i = id - 8512; tr64(wkr, W + 512 * 2048, 2048, 64, 0, i); }
  else                { int i = id - 8544; tr64(wdq, W + 576 * 2048, 2048, 1024, i & 15, i >> 4); }
}
// ---------- TB1: {W_UK, W_UV} ----------
__global__ __launch_bounds__(256)
void tb1_k(const float* __restrict__ wuk, const float* __restrict__ wuv, u16* __restrict__ W) {
  int id = blockIdx.x;
  if (id < 256) tr64(wuk, W, 512, 2048, id & 31, id >> 5);
  else { int i = id - 256; tr64(wuv, W + 2048 * 512, 512, 2048, i & 31, i >> 5); }
}
// ---------- TB2: {W_UQ, W_QR} ----------
__global__ __launch_bounds__(256)
void tb2_k(const float* __restrict__ wuq, const float* __restrict__ wqr, u16* __restrict__ W) {
  int id = blockIdx.x;
  if (id < 512) tr64(wuq, W, 1024, 2048, id & 31, id >> 5);
  else { int i = id - 512; tr64(wqr, W + 2048 * 1024, 1024, 1024, i & 15, i >> 4); }
}
// ---------- TC: W_O ----------
__global__ __launch_bounds__(256)
void tc_k(const float* __restrict__ wo, u16* __restrict__ W) {
  tr64(wo, W, 2048, 2048, blockIdx.x & 31, blockIdx.x >> 5);
}

// ---------------- GEMM: C(M,N) = A(M,K) * Bt(N,K)^T, bf16 in, fp32 acc ----------------
// BK=64 via two independent 32-wide LDS buffers (round-5 form; explicit dbuf
// prefetch measured exactly neutral in round 6 -> keep the simpler 32 KB
// version, which also leaves LDS headroom for higher occupancy).
// EPI 2: fp32 OF (y).
// EPI 4: n<2048 -> O0 bf16 (Kc); else V^T store to O1.
// EPI 5: n<2048 -> O0 (Qc); else O1 width 1024 (Qr raw).
// EPI 6: n<512 -> O0 (cKV) + OF fp32 (out_ckv); n<576 -> fused K-rope -> O1 bf16 (kr) + OF2 fp32;
//        n<1600 -> O2 width 1024 (cQ).
template <int EPI>
__global__ __launch_bounds__(256)
void gemm_bf16(const u16* __restrict__ A, const u16* __restrict__ Bt,
               u16* __restrict__ O0, u16* __restrict__ O1, u16* __restrict__ O2,
               float* __restrict__ OF, float* __restrict__ OF2,
               const u16* __restrict__ FR, int M, int N, int K) {
  __shared__ __align__(16) u16 Al[2][128 * 32];
  __shared__ __align__(16) u16 Bl[2][128 * 32];
  const int tid = threadIdx.x;
  const int ln = tid & 63, w = tid >> 6;
  const int quad = ln >> 4, l16 = ln & 15;
  const int wm = (w >> 1) * 64, wn = (w & 1) * 64;
  const int m0 = blockIdx.y * 128, n0 = blockIdx.x * 128;

  f32x4 zz = {0.f, 0.f, 0.f, 0.f};
  f32x4 acc[4][4];
#pragma unroll
  for (int i = 0; i < 4; i++)
#pragma unroll
    for (int j = 0; j < 4; j++) acc[i][j] = zz;

  const u16* aG[2];
  const u16* bG[2];
  int ldsC[2];
#pragma unroll
  for (int r = 0; r < 2; r++) {
    int i = tid + r * 256;
    int row = i >> 2, cq = (i & 3) * 8;
    aG[r] = A + (size_t)(m0 + row) * K + cq;
    int rb = n0 + row;
    if (rb > N - 1) rb = N - 1;  // clamp for partial tiles (dup rows, cols discarded)
    bG[r] = Bt + (size_t)rb * K + cq;
    ldsC[r] = ((tid & ~63) + r * 256) * 8;  // wave-uniform chunk base (shorts)
  }

  for (int k = 0; k < K; k += 64) {
#pragma unroll
    for (int hh = 0; hh < 2; hh++)
#pragma unroll
      for (int r = 0; r < 2; r++) {
        ld_lds16(aG[r] + k + hh * 32, &Al[hh][ldsC[r]]);
        ld_lds16(bG[r] + k + hh * 32, &Bl[hh][ldsC[r]]);
      }
    __syncthreads();
#pragma unroll
    for (int hh = 0; hh < 2; hh++) {
      s16x8 af[4], bf[4];
#pragma unroll
      for (int f = 0; f < 4; f++)
        af[f] = *(const s16x8*)&Al[hh][(wm + f * 16 + l16) * 32 + quad * 8];
#pragma unroll
      for (int f = 0; f < 4; f++)
        bf[f] = *(const s16x8*)&Bl[hh][(wn + f * 16 + l16) * 32 + quad * 8];
#pragma unroll
      for (int i = 0; i < 4; i++)
#pragma unroll
        for (int j = 0; j < 4; j++)
          acc[i][j] = __builtin_amdgcn_mfma_f32_16x16x32_bf16(af[i], bf[j], acc[i][j], 0, 0, 0);
    }
    __syncthreads();
  }

#pragma unroll
  for (int fm = 0; fm < 4; fm++) {
#pragma unroll
    for (int fn = 0; fn < 4; fn++) {
      int n = n0 + wn + fn * 16 + l16;
      int mb = m0 + wm + fm * 16 + quad * 4;
      if (EPI == 2) {
        if (n < N) {
#pragma unroll
          for (int rg = 0; rg < 4; rg++) OF[(size_t)(mb + rg) * N + n] = acc[fm][fn][rg];
        }
      } else if (EPI == 4) {
        if (n < 2048) {
#pragma unroll
          for (int rg = 0; rg < 4; rg++) O0[(size_t)(mb + rg) * 2048 + n] = f2b(acc[fm][fn][rg]);
        } else {
          int hd = n - 2048, b = mb >> 11, t = mb & 2047;
          ushort4 v;
          v.x = f2b(acc[fm][fn][0]); v.y = f2b(acc[fm][fn][1]);
          v.z = f2b(acc[fm][fn][2]); v.w = f2b(acc[fm][fn][3]);
          *(ushort4*)(O1 + ((size_t)(b * 2048 + hd) * 2048 + t)) = v;
        }
      } else if (EPI == 5) {
        if (n < 2048) {
#pragma unroll
          for (int rg = 0; rg < 4; rg++) O0[(size_t)(mb + rg) * 2048 + n] = f2b(acc[fm][fn][rg]);
        } else {
#pragma unroll
          for (int rg = 0; rg < 4; rg++) O1[(size_t)(mb + rg) * 1024 + (n - 2048)] = f2b(acc[fm][fn][rg]);
        }
      } else {  // EPI 6
        if (n < 512) {
#pragma unroll
          for (int rg = 0; rg < 4; rg++) {
            float v = acc[fm][fn][rg];
            O0[(size_t)(mb + rg) * 512 + n] = f2b(v);
            OF[(size_t)(mb + rg) * 512 + n] = v;
          }
        } else if (n < 576) {
          // fused K-rope: adjacent lanes hold the (even,odd) pair
          int r = n - 512, r2 = r >> 1, odd = r & 1;
#pragma unroll
          for (int rg = 0; rg < 4; rg++) {
            float v = acc[fm][fn][rg];
            float p = __shfl_xor(v, 1);
            int t = mb + rg;
            float a = b2f(FR[(size_t)(t & 2047) * 32 + r2]);
            float sn, cs;
            __sincosf(a, &sn, &cs);
            float y = odd ? (p * sn + v * cs) : (v * cs - p * sn);
            O1[(size_t)t * 64 + r] = f2b(y);
            OF2[(size_t)t * 64 + r] = y;
          }
        } else if (n < 1600) {
#pragma unroll
          for (int rg = 0; rg < 4; rg++) O2[(size_t)(mb + rg) * 1024 + (n - 576)] = f2b(acc[fm][fn][rg]);
        }
      }
    }
  }
}

// ---------------- flash attention (S^T formulation, 64-key tiles, 128-q blocks) ----------------
// grid (bh=32, tile=16): 512-thread blocks (8 waves), each covering 128 q-rows.
// BALANCED y remap: y_eff = (yb<8) ? yb : 23-yb, so block ids i and i+256
// (the pair round-robin assignment puts on one CU at 2 blocks/CU) carry
// q-tiles (y_eff, 15-y_eff) -> per-CU tile total is uniformly 34 (was 20..48
// with the direct mapping -> 2.4x per-CU imbalance set the wall clock).
// Longest tile still dispatches in the first half; same-bh blocks keep id%8
// => same XCD for KV L2 locality.
// Waves fully above a key-tile (k0 > qw+15) skip compute (barriers kept).
// s_setprio(1) wraps the QK^T and PV MFMA clusters (T5, attn-proven +4-7%).
// P feeds PV DIRECTLY from registers: Vt key-columns are stored PERMUTED at
// staging time so the S^T output lane layout is already a valid PV A-fragment
// (Vt col c = 32*(key>>5) + ((key>>2)&3)*8 + ((key>>4)&1)*4 + (key&3)).
// launch_bounds (512,2): no VGPR clamp (round-2 lesson: forcing waves/EU
// causes accumulator spills); natural ~80 VGPR.
#define KT_S 200  // 64 keys x 192e (+pad): 100 dwords = 4 mod 32 -> 2-way reads (free)
#define VT_S 72   // 144 rows x 64 keys (+pad): 36 dwords
__global__ __launch_bounds__(512, 2)
void flash_attn(const u16* __restrict__ Qc, const u16* __restrict__ Qr,
                const u16* __restrict__ Kc, const u16* __restrict__ Kr,
                const u16* __restrict__ VT, const u16* __restrict__ fr,
                u16* __restrict__ O) {
  __shared__ __align__(16) u16 Kt[64 * KT_S];      // 25.6 KB [key][e]
  __shared__ __align__(16) u16 Vt[144 * VT_S];     // 20.7 KB [hd + 16 ones rows][perm key]

  const int tid = threadIdx.x;
  const int ln = tid & 63, w = tid >> 6;            // w = 0..7
  const int quad = ln >> 4, l16 = ln & 15;
  const int bh = blockIdx.x, b = bh >> 4, h = bh & 15;

  // ones rows 128..143 (row-sum trick); written once (perm-invariant: all 1.0)
  for (int i = tid; i < 1024; i += 512) Vt[(128 + (i >> 6)) * VT_S + (i & 63)] = 0x3F80;

  // staging maps (tile-invariant): K = 64 keys x 24 chunks, V = 128 rows x 8 chunks
  const u16* kBase[3]; int kStep[3], kLds[3];
#pragma unroll
  for (int r = 0; r < 3; r++) {
    int i = tid + r * 512;
    int key = i / 24, c = i - key * 24;
    kLds[r] = key * KT_S + c * 8;
    if (c < 16) { kBase[r] = Kc + ((size_t)(b * T_ + key) * DM + h * HD_ + c * 8); kStep[r] = 64 * DM; }
    else        { kBase[r] = Kr + ((size_t)(b * T_ + key) * R_ + (c - 16) * 8);    kStep[r] = 64 * R_; }
  }
  // V: each lane loads 8 consecutive keys (group c); they land as two 4-key
  // runs at the permuted columns colA and colA+8 (see perm above).
  const u16* vBase[2]; int vLds[2];
#pragma unroll
  for (int r = 0; r < 2; r++) {
    int i = tid + r * 512;
    int row = i >> 3, c = i & 7, c2 = c & 3;
    vLds[r] = row * VT_S + (c >> 2) * 32 + ((2 * c2) & 3) * 8 + (c2 >> 1) * 4;
    vBase[r] = VT + ((size_t)(bh * HD_ + row) * T_ + c * 8);
  }

  f32x4 zz = {0.f, 0.f, 0.f, 0.f};
  const int yb = blockIdx.y;
  const int ye = (yb < 8) ? yb : 23 - yb;        // balanced pairing: ids i, i+256 sum to 34 tiles
  const int q0 = (15 - ye) * 128;                // ye=0 (first-dispatched) is the longest
  const int qw = q0 + w * 16;

  // Q fragments (B-operand: n=l16 (q), k=quad*8+j (e)); rope fused for e>=128
  s16x8 qf[6];
  {
    int t = qw + l16;
    const u16* p = Qc + ((size_t)(b * T_ + t) * DM + h * HD_ + quad * 8);
#pragma unroll
    for (int f = 0; f < 4; f++) qf[f] = *(const s16x8*)(p + f * 32);
    const u16* pr = Qr + ((size_t)(b * T_ + t) * (H_ * R_) + h * R_ + quad * 8);
#pragma unroll
    for (int half = 0; half < 2; half++) {
      s16x8 v = *(const s16x8*)(pr + half * 32);
      s16x8 o2;
#pragma unroll
      for (int p2 = 0; p2 < 4; p2++) {
        float a = b2f(fr[t * 32 + half * 16 + quad * 4 + p2]);
        float sn, cs;
        __sincosf(a, &sn, &cs);
        float x0 = b2f((u16)v[2 * p2]), x1 = b2f((u16)v[2 * p2 + 1]);
        o2[2 * p2] = (short)f2b(x0 * cs - x1 * sn);
        o2[2 * p2 + 1] = (short)f2b(x0 * sn + x1 * cs);
      }
      qf[4 + half] = o2;
    }
  }

  f32x4 o[9];
#pragma unroll
  for (int f = 0; f < 9; f++) o[f] = zz;
  float mL = -1e30f;  // running max for q = qw + l16

  // prefetch tile k0=0
  const u16* pk[3]; const u16* pv[2];
  s16x8 kv[3], vv[2];
#pragma unroll
  for (int r = 0; r < 3; r++) { pk[r] = kBase[r]; kv[r] = *(const s16x8*)pk[r]; }
#pragma unroll
  for (int r = 0; r < 2; r++) { pv[r] = vBase[r]; vv[r] = *(const s16x8*)pv[r]; }

  const int nk = q0 + 128;
  for (int k0 = 0; k0 < nk; k0 += 64) {
    __syncthreads();  // previous tile fully consumed
#pragma unroll
    for (int r = 0; r < 3; r++) *(s16x8*)&Kt[kLds[r]] = kv[r];
#pragma unroll
    for (int r = 0; r < 2; r++) {
      union { s16x8 v; uint4 u; } V_; V_.v = vv[r];
      uint2 lo; lo.x = V_.u.x; lo.y = V_.u.y;
      uint2 hi; hi.x = V_.u.z; hi.y = V_.u.w;
      *(uint2*)&Vt[vLds[r]] = lo;
      *(uint2*)&Vt[vLds[r] + 8] = hi;
    }
    __syncthreads();  // staging visible
    if (k0 + 64 < nk) {
#pragma unroll
      for (int r = 0; r < 3; r++) { pk[r] += kStep[r]; kv[r] = *(const s16x8*)pk[r]; }
#pragma unroll
      for (int r = 0; r < 2; r++) { pv[r] += 64; vv[r] = *(const s16x8*)pv[r]; }
    }
    if (k0 > qw + 15) continue;  // tile fully above this wave's causal range

    // S^T = K * Q^T : A-frag = K rows (keys), B-frag = Q (regs)
    f32x4 s[4];
#pragma unroll
    for (int kg = 0; kg < 4; kg++) s[kg] = zz;
    __builtin_amdgcn_s_setprio(1);
#pragma unroll
    for (int e = 0; e < 6; e++)
#pragma unroll
      for (int kg = 0; kg < 4; kg++) {
        s16x8 kf = *(const s16x8*)&Kt[(kg * 16 + l16) * KT_S + e * 32 + quad * 8];
        s[kg] = __builtin_amdgcn_mfma_f32_16x16x32_bf16(kf, qf[e], s[kg], 0, 0, 0);
      }
    __builtin_amdgcn_s_setprio(0);
    // lane holds S^T[key = k0 + kg*16 + quad*4 + rg][q = qw + l16]
    const int q = qw + l16;
    float sv[16];
    if (k0 + 63 <= qw) {  // wave-uniform full tile: no mask needed
#pragma unroll
      for (int kg = 0; kg < 4; kg++)
#pragma unroll
        for (int rg = 0; rg < 4; rg++) sv[kg * 4 + rg] = s[kg][rg] * SCALE2;
    } else {
#pragma unroll
      for (int kg = 0; kg < 4; kg++)
#pragma unroll
        for (int rg = 0; rg < 4; rg++) {
          int key = k0 + kg * 16 + quad * 4 + rg;
          sv[kg * 4 + rg] = (key > q) ? -1e30f : s[kg][rg] * SCALE2;
        }
    }
    // tree max (short critical chain; compiler can fuse to v_max3)
    float mxa = fmaxf(fmaxf(sv[0], sv[1]), fmaxf(sv[2], sv[3]));
    float mxb = fmaxf(fmaxf(sv[4], sv[5]), fmaxf(sv[6], sv[7]));
    float mxc = fmaxf(fmaxf(sv[8], sv[9]), fmaxf(sv[10], sv[11]));
    float mxd = fmaxf(fmaxf(sv[12], sv[13]), fmaxf(sv[14], sv[15]));
    float mx = fmaxf(fmaxf(mxa, mxb), fmaxf(mxc, mxd));
    mx = fmaxf(mx, __shfl_xor(mx, 16));
    mx = fmaxf(mx, __shfl_xor(mx, 32));
    if (__any(mx > mL)) {  // new max somewhere in wave: rescale path
      float mn = fmaxf(mL, mx);
      float alpha = exp2f(mL - mn);
      mL = mn;
      float al[4];
#pragma unroll
      for (int rg = 0; rg < 4; rg++) al[rg] = __shfl(alpha, (ln & 48) | (quad * 4 + rg));
#pragma unroll
      for (int f = 0; f < 9; f++)
#pragma unroll
        for (int rg = 0; rg < 4; rg++) o[f][rg] *= al[rg];
    }
    float p[16];
#pragma unroll
    for (int j = 0; j < 16; j++) p[j] = exp2f(sv[j] - mL);
    // pack P in place: pw[0..3] IS the PV A-fragment for keys k0..k0+31
    // (matching Vt's permuted columns), pw[4..7] for keys k0+32..k0+63.
    // No LDS, no cross-lane ops.
    union { unsigned pw[8]; s16x8 pa[2]; } P_;
#pragma unroll
    for (int kg = 0; kg < 4; kg++) {
      P_.pw[kg * 2 + 0] = pk2(p[kg * 4 + 0], p[kg * 4 + 1]);
      P_.pw[kg * 2 + 1] = pk2(p[kg * 4 + 2], p[kg * 4 + 3]);
    }
    // PV: A = P (m=q=l16, k=perm key), B = V^T rows (f=8 -> ones rows = row sums)
    __builtin_amdgcn_s_setprio(1);
#pragma unroll
    for (int f = 0; f < 9; f++) {
      s16x8 vb0 = *(const s16x8*)&Vt[(f * 16 + l16) * VT_S + quad * 8];
      o[f] = __builtin_amdgcn_mfma_f32_16x16x32_bf16(P_.pa[0], vb0, o[f], 0, 0, 0);
      s16x8 vb1 = *(const s16x8*)&Vt[(f * 16 + l16) * VT_S + 32 + quad * 8];
      o[f] = __builtin_amdgcn_mfma_f32_16x16x32_bf16(P_.pa[1], vb1, o[f], 0, 0, 0);
    }
    __builtin_amdgcn_s_setprio(0);
  }

  float inv[4];
#pragma unroll
  for (int rg = 0; rg < 4; rg++) inv[rg] = 1.0f / o[8][rg];  // row-sum from ones rows
#pragma unroll
  for (int f = 0; f < 8; f++) {
#pragma unroll
    for (int rg = 0; rg < 4; rg++) {
      int qq = qw + quad * 4 + rg;
      O[(size_t)(b * T_ + qq) * DM + h * HD_ + f * 16 + l16] = f2b(o[f][rg] * inv[rg]);
    }
  }
}

// ---------------- launch ----------------
extern "C" void kernel_launch(void* const* d_in, const int* in_sizes, int n_in,
                              void* d_out, int out_size, void* d_ws, size_t ws_size,
                              hipStream_t stream) {
  const float* x    = (const float*)d_in[0];
  const float* fr   = (const float*)d_in[1];
  const float* wdkv = (const float*)d_in[2];
  const float* wuk  = (const float*)d_in[3];
  const float* wuv  = (const float*)d_in[4];
  const float* wkr  = (const float*)d_in[5];
  const float* wdq  = (const float*)d_in[6];
  const float* wuq  = (const float*)d_in[7];
  const float* wqr  = (const float*)d_in[8];
  const float* wo   = (const float*)d_in[9];
  u16* ws = (u16*)d_ws;

  const int M1 = 1048576;
  u16* x_bf  = ws;                 // 8M (dead after gx) -> Om overlays
  u16* Om    = ws;                 // 8M [flash..g8]
  u16* Kc    = ws + 8 * M1;        // 8M (b,t,h*hd)
  u16* VTm   = ws + 16 * M1;       // 8M (b,h*hd,t)
  u16* Qc    = ws + 24 * M1;       // 8M (b,t,h*hd)
  u16* Qr    = ws + 32 * M1;       // 4M (b,t,h,r) RAW (rope fused in flash)
  u16* W     = ws + 36 * M1;       // 4M transpose arena (serial reuse)
  u16* cKV   = ws + 40 * M1;       // 2M
  u16* cQ    = ws + 42 * M1;       // 4M
  u16* fr_bf = ws + 46 * M1;       // 65536
  u16* kr_bf = fr_bf + 65536;      // 262144

  float* out_y   = (float*)d_out;              // (b,t,2048)
  float* out_ckv = (float*)d_out + 8388608;    // (b,t,512)
  float* out_kr  = (float*)d_out + 10485760;   // (b,t,64)
  (void)in_sizes; (void)n_in; (void)out_size; (void)ws_size;

  dim3 blk(256);

  // TA: conv x, conv fr, transpose gx weights
  ta_k<<<dim3(9056), blk, 0, stream>>>(x, fr, x_bf, fr_bf, wdkv, wkr, wdq, W);
  // gx: [cKV | K_r(rope) | cQ] = x @ [W_DKV | W_KR | W_DQ]
  gemm_bf16<6><<<dim3(13, 32), blk, 0, stream>>>(x_bf, W, cKV, kr_bf, cQ, out_ckv, out_kr, fr_bf,
                                                 4096, 1600, 2048);
  // gkv: [K_c | V^T] = c_KV @ [W_UK | W_UV]
  tb1_k<<<dim3(512), blk, 0, stream>>>(wuk, wuv, W);
  gemm_bf16<4><<<dim3(32, 32), blk, 0, stream>>>(cKV, W, Kc, VTm, nullptr, nullptr, nullptr, nullptr,
                                                 4096, 4096, 512);
  // gq: [Q_c | Q_r-raw] = c_Q @ [W_UQ | W_QR]
  tb2_k<<<dim3(768), blk, 0, stream>>>(wuq, wqr, W);
  gemm_bf16<5><<<dim3(24, 32), blk, 0, stream>>>(cQ, W, Qc, Qr, nullptr, nullptr, nullptr, nullptr,
                                                 4096, 3072, 1024);
  // attention (Om overlays dead x_bf): 128-q blocks, 8 waves, balanced y remap
  flash_attn<<<dim3(32, 16), dim3(512), 0, stream>>>(Qc, Qr, Kc, kr_bf, VTm, fr_bf, Om);
  // y = attn_out @ W_O
  tc_k<<<dim3(1024), blk, 0, stream>>>(wo, W);
  gemm_bf16<2><<<dim3(16, 32), blk, 0, stream>>>(Om, W, nullptr, nullptr, nullptr, out_y, nullptr,
                                                 nullptr, 4096, 2048, 2048);
}

// Round 8
// 378.596 us; speedup vs baseline: 1.0853x; 1.0853x over previous
//
#include <hip/hip_runtime.h>
#include <stdint.h>

typedef unsigned short u16;
typedef __attribute__((ext_vector_type(8))) short s16x8;
typedef __attribute__((ext_vector_type(4))) float f32x4;

#define B_   2
#define T_   2048
#define DM   2048
#define H_   16
#define HD_  128
#define R_   64
#define E_   192
// 1/sqrt(192) * log2(e): softmax in base-2 domain
#define SCALE2 0.104117542f

__device__ __forceinline__ u16 f2b(float f) {
  union { float f; uint32_t u; } x; x.f = f;
  uint32_t u = x.u;
  return (u16)((u + 0x7FFFu + ((u >> 16) & 1u)) >> 16);  // RNE
}
__device__ __forceinline__ float b2f(u16 h) {
  union { uint32_t u; float f; } x; x.u = ((uint32_t)h) << 16;
  return x.f;
}
// pack two f32 -> two bf16 (truncation; used only for P which is renormalized by row-sum)
__device__ __forceinline__ unsigned pk2(float a, float b) {
  union { float f; unsigned u; } A, B; A.f = a; B.f = b;
  return (B.u & 0xFFFF0000u) | (A.u >> 16);
}
// async global->LDS, 16B/lane; LDS dest = wave-uniform base + lane*16
__device__ __forceinline__ void ld_lds16(const void* g, void* l) {
  __builtin_amdgcn_global_load_lds((const __attribute__((address_space(1))) void*)g,
                                   (__attribute__((address_space(3))) void*)l,
                                   16, 0, 0);
}

// ---------- device helpers: conv + 64x64 transpose tile ----------
__device__ __forceinline__ void conv_dev(const float* __restrict__ in, u16* __restrict__ out, int i) {
  float4 v = *(const float4*)(in + (size_t)i * 4);
  ushort4 o;
  o.x = f2b(v.x); o.y = f2b(v.y); o.z = f2b(v.z); o.w = f2b(v.w);
  *(ushort4*)(out + (size_t)i * 4) = o;
}
__device__ __forceinline__ void tr64(const float* __restrict__ in, u16* __restrict__ out,
                                     int K, int N, int bx, int by) {
  __shared__ u16 t[64][65];
  int bn = bx * 64, bk = by * 64;
  int tid = threadIdx.x;
  int r0 = tid >> 4, c0 = (tid & 15) * 4;
#pragma unroll
  for (int rr = 0; rr < 64; rr += 16) {
    float4 v = *(const float4*)(in + (size_t)(bk + r0 + rr) * N + bn + c0);
    t[r0 + rr][c0 + 0] = f2b(v.x); t[r0 + rr][c0 + 1] = f2b(v.y);
    t[r0 + rr][c0 + 2] = f2b(v.z); t[r0 + rr][c0 + 3] = f2b(v.w);
  }
  __syncthreads();
#pragma unroll
  for (int rr = 0; rr < 64; rr += 16) {
    ushort4 v;
    v.x = t[c0 + 0][r0 + rr]; v.y = t[c0 + 1][r0 + rr];
    v.z = t[c0 + 2][r0 + rr]; v.w = t[c0 + 3][r0 + rr];
    *(ushort4*)(out + (size_t)(bn + r0 + rr) * K + bk + c0) = v;
  }
}

// ---------- TA: conv x, conv fr, transpose {W_DKV, W_KR, W_DQ} into gx arena.
// Merged mode (grid 10336): also transpose {W_UK, W_UV} -> UKUV and
// {W_UQ, W_QR} -> UQQR (weight-only, independent of everything downstream
// until kvq). Fallback mode launches only 9056 blocks (ext pointers unused).
__global__ __launch_bounds__(256)
void ta_k(const float* __restrict__ x, const float* __restrict__ fr,
          u16* __restrict__ x_bf, u16* __restrict__ fr_bf,
          const float* __restrict__ wdkv, const float* __restrict__ wkr,
          const float* __restrict__ wdq, u16* __restrict__ W,
          const float* __restrict__ wuk, const float* __restrict__ wuv,
          const float* __restrict__ wuq, const float* __restrict__ wqr,
          u16* __restrict__ UKUV, u16* __restrict__ UQQR) {
  int id = blockIdx.x;
  if (id < 8192)        conv_dev(x, x_bf, id * 256 + threadIdx.x);
  else if (id < 8256)   conv_dev(fr, fr_bf, (id - 8192) * 256 + threadIdx.x);
  else if (id < 8512) { int i = id - 8256; tr64(wdkv, W, 2048, 512, i & 7, i >> 3); }
  else if (id < 8544) { int i = id - 8512; tr64(wkr, W + 512 * 2048, 2048, 64, 0, i); }
  else if (id < 9056) { int i = id - 8544; tr64(wdq, W + 576 * 2048, 2048, 1024, i & 15, i >> 4); }
  else if (id < 9312) { int i = id - 9056; tr64(wuk, UKUV, 512, 2048, i & 31, i >> 5); }
  else if (id < 9568) { int i = id - 9312; tr64(wuv, UKUV + 2048 * 512, 512, 2048, i & 31, i >> 5); }
  else if (id < 10080){ int i = id - 9568; tr64(wuq, UQQR, 1024, 2048, i & 31, i >> 5); }
  else                { int i = id - 10080; tr64(wqr, UQQR + 2048 * 1024, 1024, 1024, i & 15, i >> 4); }
}
// ---------- TB1: {W_UK, W_UV} (fallback path only) ----------
__global__ __launch_bounds__(256)
void tb1_k(const float* __restrict__ wuk, const float* __restrict__ wuv, u16* __restrict__ W) {
  int id = blockIdx.x;
  if (id < 256) tr64(wuk, W, 512, 2048, id & 31, id >> 5);
  else { int i = id - 256; tr64(wuv, W + 2048 * 512, 512, 2048, i & 31, i >> 5); }
}
// ---------- TB2: {W_UQ, W_QR} (fallback path only) ----------
__global__ __launch_bounds__(256)
void tb2_k(const float* __restrict__ wuq, const float* __restrict__ wqr, u16* __restrict__ W) {
  int id = blockIdx.x;
  if (id < 512) tr64(wuq, W, 1024, 2048, id & 31, id >> 5);
  else { int i = id - 512; tr64(wqr, W + 2048 * 1024, 1024, 1024, i & 15, i >> 4); }
}
// ---------- TC: W_O ----------
__global__ __launch_bounds__(256)
void tc_k(const float* __restrict__ wo, u16* __restrict__ W) {
  tr64(wo, W, 2048, 2048, blockIdx.x & 31, blockIdx.x >> 5);
}

// ---------------- GEMM body: C(M,N) = A(M,K) * Bt(N,K)^T, bf16 in, fp32 acc ----------------
// BK=64 via two independent 32-wide LDS buffers (proven round-5 form; explicit
// dbuf prefetch measured exactly neutral in round 6).
// EPI 2: fp32 OF (y).
// EPI 4: n<2048 -> O0 bf16 (Kc); else V^T store to O1.
// EPI 5: n<2048 -> O0 (Qc); else O1 width 1024 (Qr raw).
// EPI 6: n<512 -> O0 (cKV) + OF fp32 (out_ckv); n<576 -> fused K-rope -> O1 bf16 (kr) + OF2 fp32;
//        n<1600 -> O2 width 1024 (cQ).
template <int EPI>
__device__ __forceinline__ void gemm_body(u16* Al, u16* Bl,
               const u16* __restrict__ A, const u16* __restrict__ Bt,
               u16* __restrict__ O0, u16* __restrict__ O1, u16* __restrict__ O2,
               float* __restrict__ OF, float* __restrict__ OF2,
               const u16* __restrict__ FR, int M, int N, int K, int bx, int by) {
  const int tid = threadIdx.x;
  const int ln = tid & 63, w = tid >> 6;
  const int quad = ln >> 4, l16 = ln & 15;
  const int wm = (w >> 1) * 64, wn = (w & 1) * 64;
  const int m0 = by * 128, n0 = bx * 128;

  f32x4 zz = {0.f, 0.f, 0.f, 0.f};
  f32x4 acc[4][4];
#pragma unroll
  for (int i = 0; i < 4; i++)
#pragma unroll
    for (int j = 0; j < 4; j++) acc[i][j] = zz;

  const u16* aG[2];
  const u16* bG[2];
  int ldsC[2];
#pragma unroll
  for (int r = 0; r < 2; r++) {
    int i = tid + r * 256;
    int row = i >> 2, cq = (i & 3) * 8;
    aG[r] = A + (size_t)(m0 + row) * K + cq;
    int rb = n0 + row;
    if (rb > N - 1) rb = N - 1;  // clamp for partial tiles (dup rows, cols discarded)
    bG[r] = Bt + (size_t)rb * K + cq;
    ldsC[r] = ((tid & ~63) + r * 256) * 8;  // wave-uniform chunk base (shorts)
  }

  for (int k = 0; k < K; k += 64) {
#pragma unroll
    for (int hh = 0; hh < 2; hh++)
#pragma unroll
      for (int r = 0; r < 2; r++) {
        ld_lds16(aG[r] + k + hh * 32, &Al[hh * 4096 + ldsC[r]]);
        ld_lds16(bG[r] + k + hh * 32, &Bl[hh * 4096 + ldsC[r]]);
      }
    __syncthreads();
#pragma unroll
    for (int hh = 0; hh < 2; hh++) {
      s16x8 af[4], bf[4];
#pragma unroll
      for (int f = 0; f < 4; f++)
        af[f] = *(const s16x8*)&Al[hh * 4096 + (wm + f * 16 + l16) * 32 + quad * 8];
#pragma unroll
      for (int f = 0; f < 4; f++)
        bf[f] = *(const s16x8*)&Bl[hh * 4096 + (wn + f * 16 + l16) * 32 + quad * 8];
#pragma unroll
      for (int i = 0; i < 4; i++)
#pragma unroll
        for (int j = 0; j < 4; j++)
          acc[i][j] = __builtin_amdgcn_mfma_f32_16x16x32_bf16(af[i], bf[j], acc[i][j], 0, 0, 0);
    }
    __syncthreads();
  }

#pragma unroll
  for (int fm = 0; fm < 4; fm++) {
#pragma unroll
    for (int fn = 0; fn < 4; fn++) {
      int n = n0 + wn + fn * 16 + l16;
      int mb = m0 + wm + fm * 16 + quad * 4;
      if (EPI == 2) {
        if (n < N) {
#pragma unroll
          for (int rg = 0; rg < 4; rg++) OF[(size_t)(mb + rg) * N + n] = acc[fm][fn][rg];
        }
      } else if (EPI == 4) {
        if (n < 2048) {
#pragma unroll
          for (int rg = 0; rg < 4; rg++) O0[(size_t)(mb + rg) * 2048 + n] = f2b(acc[fm][fn][rg]);
        } else {
          int hd = n - 2048, b = mb >> 11, t = mb & 2047;
          ushort4 v;
          v.x = f2b(acc[fm][fn][0]); v.y = f2b(acc[fm][fn][1]);
          v.z = f2b(acc[fm][fn][2]); v.w = f2b(acc[fm][fn][3]);
          *(ushort4*)(O1 + ((size_t)(b * 2048 + hd) * 2048 + t)) = v;
        }
      } else if (EPI == 5) {
        if (n < 2048) {
#pragma unroll
          for (int rg = 0; rg < 4; rg++) O0[(size_t)(mb + rg) * 2048 + n] = f2b(acc[fm][fn][rg]);
        } else {
#pragma unroll
          for (int rg = 0; rg < 4; rg++) O1[(size_t)(mb + rg) * 1024 + (n - 2048)] = f2b(acc[fm][fn][rg]);
        }
      } else {  // EPI 6
        if (n < 512) {
#pragma unroll
          for (int rg = 0; rg < 4; rg++) {
            float v = acc[fm][fn][rg];
            O0[(size_t)(mb + rg) * 512 + n] = f2b(v);
            OF[(size_t)(mb + rg) * 512 + n] = v;
          }
        } else if (n < 576) {
          // fused K-rope: adjacent lanes hold the (even,odd) pair
          int r = n - 512, r2 = r >> 1, odd = r & 1;
#pragma unroll
          for (int rg = 0; rg < 4; rg++) {
            float v = acc[fm][fn][rg];
            float p = __shfl_xor(v, 1);
            int t = mb + rg;
            float a = b2f(FR[(size_t)(t & 2047) * 32 + r2]);
            float sn, cs;
            __sincosf(a, &sn, &cs);
            float y = odd ? (p * sn + v * cs) : (v * cs - p * sn);
            O1[(size_t)t * 64 + r] = f2b(y);
            OF2[(size_t)t * 64 + r] = y;
          }
        } else if (n < 1600) {
#pragma unroll
          for (int rg = 0; rg < 4; rg++) O2[(size_t)(mb + rg) * 1024 + (n - 576)] = f2b(acc[fm][fn][rg]);
        }
      }
    }
  }
}

template <int EPI>
__global__ __launch_bounds__(256)
void gemm_bf16(const u16* __restrict__ A, const u16* __restrict__ Bt,
               u16* __restrict__ O0, u16* __restrict__ O1, u16* __restrict__ O2,
               float* __restrict__ OF, float* __restrict__ OF2,
               const u16* __restrict__ FR, int M, int N, int K) {
  __shared__ __align__(16) u16 Al[2 * 128 * 32];
  __shared__ __align__(16) u16 Bl[2 * 128 * 32];
  gemm_body<EPI>(Al, Bl, A, Bt, O0, O1, O2, OF, OF2, FR, M, N, K, blockIdx.x, blockIdx.y);
}

// ---------- merged gkv+gq: 1792 blocks, gq (K=1024, longer) dispatched first.
// gkv and gq are independent (both consume gx outputs); fusing them raises
// per-CU concurrency from 3-4 to 7 blocks and overlaps their ramps/tails.
__global__ __launch_bounds__(256)
void kvq_k(const u16* __restrict__ cKV, const u16* __restrict__ UKUV,
           u16* __restrict__ Kc, u16* __restrict__ VT,
           const u16* __restrict__ cQ, const u16* __restrict__ UQQR,
           u16* __restrict__ Qc, u16* __restrict__ Qr) {
  __shared__ __align__(16) u16 Al[2 * 128 * 32];
  __shared__ __align__(16) u16 Bl[2 * 128 * 32];
  int id = blockIdx.x;
  if (id < 768) {       // gq: 24 x 32 tiles of (4096, 3072), K=1024
    gemm_body<5>(Al, Bl, cQ, UQQR, Qc, Qr, nullptr, nullptr, nullptr, nullptr,
                 4096, 3072, 1024, id % 24, id / 24);
  } else {              // gkv: 32 x 32 tiles of (4096, 4096), K=512
    int j = id - 768;
    gemm_body<4>(Al, Bl, cKV, UKUV, Kc, VT, nullptr, nullptr, nullptr, nullptr,
                 4096, 4096, 512, j & 31, j >> 5);
  }
}

// ---------------- flash attention (S^T formulation, 64-key tiles, 128-q blocks) ----------------
// ROUND-5 FORM (reverted): round-7's balanced-y remap + setprio regressed
// 95->115 us. setprio starves the prefetch-issuing waves in this 8-wave
// barrier-synced structure (m190 lockstep case, not m191 independent-wave);
// the remap can't beat the longest block's single-block-rate floor.
// grid (bh=32, tile=16): 512-thread blocks (8 waves), each covering 128 q-rows.
// K/V staging per key-tile is amortized over 8 waves; grid 512 = 2 blocks/CU.
// Longest tile at y=0 dispatches first; same-bh blocks keep id%8 => same XCD.
// Waves fully above a key-tile (k0 > qw+15) skip compute (barriers kept).
// P feeds PV DIRECTLY from registers: Vt key-columns are stored PERMUTED at
// staging time so the S^T output lane layout is already a valid PV A-fragment
// (Vt col c = 32*(key>>5) + ((key>>2)&3)*8 + ((key>>4)&1)*4 + (key&3)).
// launch_bounds (512,2): no VGPR clamp (round-2 lesson: forcing waves/EU
// causes accumulator spills); natural ~80 VGPR.
#define KT_S 200  // 64 keys x 192e (+pad): 100 dwords = 4 mod 32 -> 2-way reads (free)
#define VT_S 72   // 144 rows x 64 keys (+pad): 36 dwords
__global__ __launch_bounds__(512, 2)
void flash_attn(const u16* __restrict__ Qc, const u16* __restrict__ Qr,
                const u16* __restrict__ Kc, const u16* __restrict__ Kr,
                const u16* __restrict__ VT, const u16* __restrict__ fr,
                u16* __restrict__ O) {
  __shared__ __align__(16) u16 Kt[64 * KT_S];      // 25.6 KB [key][e]
  __shared__ __align__(16) u16 Vt[144 * VT_S];     // 20.7 KB [hd + 16 ones rows][perm key]

  const int tid = threadIdx.x;
  const int ln = tid & 63, w = tid >> 6;            // w = 0..7
  const int quad = ln >> 4, l16 = ln & 15;
  const int bh = blockIdx.x, b = bh >> 4, h = bh & 15;

  // ones rows 128..143 (row-sum trick); written once (perm-invariant: all 1.0)
  for (int i = tid; i < 1024; i += 512) Vt[(128 + (i >> 6)) * VT_S + (i & 63)] = 0x3F80;

  // staging maps (tile-invariant): K = 64 keys x 24 chunks, V = 128 rows x 8 chunks
  const u16* kBase[3]; int kStep[3], kLds[3];
#pragma unroll
  for (int r = 0; r < 3; r++) {
    int i = tid + r * 512;
    int key = i / 24, c = i - key * 24;
    kLds[r] = key * KT_S + c * 8;
    if (c < 16) { kBase[r] = Kc + ((size_t)(b * T_ + key) * DM + h * HD_ + c * 8); kStep[r] = 64 * DM; }
    else        { kBase[r] = Kr + ((size_t)(b * T_ + key) * R_ + (c - 16) * 8);    kStep[r] = 64 * R_; }
  }
  // V: each lane loads 8 consecutive keys (group c); they land as two 4-key
  // runs at the permuted columns colA and colA+8 (see perm above).
  const u16* vBase[2]; int vLds[2];
#pragma unroll
  for (int r = 0; r < 2; r++) {
    int i = tid + r * 512;
    int row = i >> 3, c = i & 7, c2 = c & 3;
    vLds[r] = row * VT_S + (c >> 2) * 32 + ((2 * c2) & 3) * 8 + (c2 >> 1) * 4;
    vBase[r] = VT + ((size_t)(bh * HD_ + row) * T_ + c * 8);
  }

  f32x4 zz = {0.f, 0.f, 0.f, 0.f};
  const int q0 = (15 - (int)blockIdx.y) * 128;   // y=0 dispatches first -> longest first
  const int qw = q0 + w * 16;

  // Q fragments (B-operand: n=l16 (q), k=quad*8+j (e)); rope fused for e>=128
  s16x8 qf[6];
  {
    int t = qw + l16;
    const u16* p = Qc + ((size_t)(b * T_ + t) * DM + h * HD_ + quad * 8);
#pragma unroll
    for (int f = 0; f < 4; f++) qf[f] = *(const s16x8*)(p + f * 32);
    const u16* pr = Qr + ((size_t)(b * T_ + t) * (H_ * R_) + h * R_ + quad * 8);
#pragma unroll
    for (int half = 0; half < 2; half++) {
      s16x8 v = *(const s16x8*)(pr + half * 32);
      s16x8 o2;
#pragma unroll
      for (int p2 = 0; p2 < 4; p2++) {
        float a = b2f(fr[t * 32 + half * 16 + quad * 4 + p2]);
        float sn, cs;
        __sincosf(a, &sn, &cs);
        float x0 = b2f((u16)v[2 * p2]), x1 = b2f((u16)v[2 * p2 + 1]);
        o2[2 * p2] = (short)f2b(x0 * cs - x1 * sn);
        o2[2 * p2 + 1] = (short)f2b(x0 * sn + x1 * cs);
      }
      qf[4 + half] = o2;
    }
  }

  f32x4 o[9];
#pragma unroll
  for (int f = 0; f < 9; f++) o[f] = zz;
  float mL = -1e30f;  // running max for q = qw + l16

  // prefetch tile k0=0
  const u16* pk[3]; const u16* pv[2];
  s16x8 kv[3], vv[2];
#pragma unroll
  for (int r = 0; r < 3; r++) { pk[r] = kBase[r]; kv[r] = *(const s16x8*)pk[r]; }
#pragma unroll
  for (int r = 0; r < 2; r++) { pv[r] = vBase[r]; vv[r] = *(const s16x8*)pv[r]; }

  const int nk = q0 + 128;
  for (int k0 = 0; k0 < nk; k0 += 64) {
    __syncthreads();  // previous tile fully consumed
#pragma unroll
    for (int r = 0; r < 3; r++) *(s16x8*)&Kt[kLds[r]] = kv[r];
#pragma unroll
    for (int r = 0; r < 2; r++) {
      union { s16x8 v; uint4 u; } V_; V_.v = vv[r];
      uint2 lo; lo.x = V_.u.x; lo.y = V_.u.y;
      uint2 hi; hi.x = V_.u.z; hi.y = V_.u.w;
      *(uint2*)&Vt[vLds[r]] = lo;
      *(uint2*)&Vt[vLds[r] + 8] = hi;
    }
    __syncthreads();  // staging visible
    if (k0 + 64 < nk) {
#pragma unroll
      for (int r = 0; r < 3; r++) { pk[r] += kStep[r]; kv[r] = *(const s16x8*)pk[r]; }
#pragma unroll
      for (int r = 0; r < 2; r++) { pv[r] += 64; vv[r] = *(const s16x8*)pv[r]; }
    }
    if (k0 > qw + 15) continue;  // tile fully above this wave's causal range

    // S^T = K * Q^T : A-frag = K rows (keys), B-frag = Q (regs)
    f32x4 s[4];
#pragma unroll
    for (int kg = 0; kg < 4; kg++) s[kg] = zz;
#pragma unroll
    for (int e = 0; e < 6; e++)
#pragma unroll
      for (int kg = 0; kg < 4; kg++) {
        s16x8 kf = *(const s16x8*)&Kt[(kg * 16 + l16) * KT_S + e * 32 + quad * 8];
        s[kg] = __builtin_amdgcn_mfma_f32_16x16x32_bf16(kf, qf[e], s[kg], 0, 0, 0);
      }
    // lane holds S^T[key = k0 + kg*16 + quad*4 + rg][q = qw + l16]
    const int q = qw + l16;
    float sv[16];
    if (k0 + 63 <= qw) {  // wave-uniform full tile: no mask needed
#pragma unroll
      for (int kg = 0; kg < 4; kg++)
#pragma unroll
        for (int rg = 0; rg < 4; rg++) sv[kg * 4 + rg] = s[kg][rg] * SCALE2;
    } else {
#pragma unroll
      for (int kg = 0; kg < 4; kg++)
#pragma unroll
        for (int rg = 0; rg < 4; rg++) {
          int key = k0 + kg * 16 + quad * 4 + rg;
          sv[kg * 4 + rg] = (key > q) ? -1e30f : s[kg][rg] * SCALE2;
        }
    }
    // tree max (short critical chain; compiler can fuse to v_max3)
    float mxa = fmaxf(fmaxf(sv[0], sv[1]), fmaxf(sv[2], sv[3]));
    float mxb = fmaxf(fmaxf(sv[4], sv[5]), fmaxf(sv[6], sv[7]));
    float mxc = fmaxf(fmaxf(sv[8], sv[9]), fmaxf(sv[10], sv[11]));
    float mxd = fmaxf(fmaxf(sv[12], sv[13]), fmaxf(sv[14], sv[15]));
    float mx = fmaxf(fmaxf(mxa, mxb), fmaxf(mxc, mxd));
    mx = fmaxf(mx, __shfl_xor(mx, 16));
    mx = fmaxf(mx, __shfl_xor(mx, 32));
    if (__any(mx > mL)) {  // new max somewhere in wave: rescale path
      float mn = fmaxf(mL, mx);
      float alpha = exp2f(mL - mn);
      mL = mn;
      float al[4];
#pragma unroll
      for (int rg = 0; rg < 4; rg++) al[rg] = __shfl(alpha, (ln & 48) | (quad * 4 + rg));
#pragma unroll
      for (int f = 0; f < 9; f++)
#pragma unroll
        for (int rg = 0; rg < 4; rg++) o[f][rg] *= al[rg];
    }
    float p[16];
#pragma unroll
    for (int j = 0; j < 16; j++) p[j] = exp2f(sv[j] - mL);
    // pack P in place: pw[0..3] IS the PV A-fragment for keys k0..k0+31
    // (matching Vt's permuted columns), pw[4..7] for keys k0+32..k0+63.
    // No LDS, no cross-lane ops.
    union { unsigned pw[8]; s16x8 pa[2]; } P_;
#pragma unroll
    for (int kg = 0; kg < 4; kg++) {
      P_.pw[kg * 2 + 0] = pk2(p[kg * 4 + 0], p[kg * 4 + 1]);
      P_.pw[kg * 2 + 1] = pk2(p[kg * 4 + 2], p[kg * 4 + 3]);
    }
    // PV: A = P (m=q=l16, k=perm key), B = V^T rows (f=8 -> ones rows = row sums)
#pragma unroll
    for (int f = 0; f < 9; f++) {
      s16x8 vb0 = *(const s16x8*)&Vt[(f * 16 + l16) * VT_S + quad * 8];
      o[f] = __builtin_amdgcn_mfma_f32_16x16x32_bf16(P_.pa[0], vb0, o[f], 0, 0, 0);
      s16x8 vb1 = *(const s16x8*)&Vt[(f * 16 + l16) * VT_S + 32 + quad * 8];
      o[f] = __builtin_amdgcn_mfma_f32_16x16x32_bf16(P_.pa[1], vb1, o[f], 0, 0, 0);
    }
  }

  float inv[4];
#pragma unroll
  for (int rg = 0; rg < 4; rg++) inv[rg] = 1.0f / o[8][rg];  // row-sum from ones rows
#pragma unroll
  for (int f = 0; f < 8; f++) {
#pragma unroll
    for (int rg = 0; rg < 4; rg++) {
      int qq = qw + quad * 4 + rg;
      O[(size_t)(b * T_ + qq) * DM + h * HD_ + f * 16 + l16] = f2b(o[f][rg] * inv[rg]);
    }
  }
}

// ---------------- launch ----------------
extern "C" void kernel_launch(void* const* d_in, const int* in_sizes, int n_in,
                              void* d_out, int out_size, void* d_ws, size_t ws_size,
                              hipStream_t stream) {
  const float* x    = (const float*)d_in[0];
  const float* fr   = (const float*)d_in[1];
  const float* wdkv = (const float*)d_in[2];
  const float* wuk  = (const float*)d_in[3];
  const float* wuv  = (const float*)d_in[4];
  const float* wkr  = (const float*)d_in[5];
  const float* wdq  = (const float*)d_in[6];
  const float* wuq  = (const float*)d_in[7];
  const float* wqr  = (const float*)d_in[8];
  const float* wo   = (const float*)d_in[9];
  u16* ws = (u16*)d_ws;

  const size_t M1 = 1048576;
  u16* x_bf  = ws;                 // 8M (dead after gx) -> Om overlays
  u16* Om    = ws;                 // 8M [flash..g8]
  u16* Kc    = ws + 8 * M1;        // 8M (b,t,h*hd)
  u16* VTm   = ws + 16 * M1;       // 8M (b,h*hd,t)
  u16* Qc    = ws + 24 * M1;       // 8M (b,t,h*hd)
  u16* Qr    = ws + 32 * M1;       // 4M (b,t,h,r) RAW (rope fused in flash)
  u16* W     = ws + 36 * M1;       // 4M transpose arena (serial reuse)
  u16* cKV   = ws + 40 * M1;       // 2M
  u16* cQ    = ws + 42 * M1;       // 4M
  u16* fr_bf = ws + 46 * M1;       // 65536
  u16* kr_bf = fr_bf + 65536;      // 262144
  u16* UKUV  = ws + 47 * M1;       // 2M  (merged mode only)
  u16* UQQR  = ws + 49 * M1;       // 3M  (merged mode only; ends at 52M)

  float* out_y   = (float*)d_out;              // (b,t,2048)
  float* out_ckv = (float*)d_out + 8388608;    // (b,t,512)
  float* out_kr  = (float*)d_out + 10485760;   // (b,t,64)
  (void)in_sizes; (void)n_in; (void)out_size;

  dim3 blk(256);
  const bool merged = ws_size >= (size_t)52 * M1 * 2;  // need 104 MiB of workspace

  if (merged) {
    // TA: conv x, conv fr, ALL weight transposes (gx arena + UKUV + UQQR)
    ta_k<<<dim3(10336), blk, 0, stream>>>(x, fr, x_bf, fr_bf, wdkv, wkr, wdq, W,
                                          wuk, wuv, wuq, wqr, UKUV, UQQR);
    // gx: [cKV | K_r(rope) | cQ] = x @ [W_DKV | W_KR | W_DQ]
    gemm_bf16<6><<<dim3(13, 32), blk, 0, stream>>>(x_bf, W, cKV, kr_bf, cQ, out_ckv, out_kr, fr_bf,
                                                   4096, 1600, 2048);
    // merged gkv+gq: 1792 blocks (7/CU), gq first (longer K)
    kvq_k<<<dim3(1792), blk, 0, stream>>>(cKV, UKUV, Kc, VTm, cQ, UQQR, Qc, Qr);
  } else {
    // fallback: round-5 sequence (93 MB high-water)
    ta_k<<<dim3(9056), blk, 0, stream>>>(x, fr, x_bf, fr_bf, wdkv, wkr, wdq, W,
                                         wuk, wuv, wuq, wqr, UKUV, UQQR);
    gemm_bf16<6><<<dim3(13, 32), blk, 0, stream>>>(x_bf, W, cKV, kr_bf, cQ, out_ckv, out_kr, fr_bf,
                                                   4096, 1600, 2048);
    tb1_k<<<dim3(512), blk, 0, stream>>>(wuk, wuv, W);
    gemm_bf16<4><<<dim3(32, 32), blk, 0, stream>>>(cKV, W, Kc, VTm, nullptr, nullptr, nullptr,
                                                   nullptr, 4096, 4096, 512);
    tb2_k<<<dim3(768), blk, 0, stream>>>(wuq, wqr, W);
    gemm_bf16<5><<<dim3(24, 32), blk, 0, stream>>>(cQ, W, Qc, Qr, nullptr, nullptr, nullptr,
                                                   nullptr, 4096, 3072, 1024);
  }
  // attention (Om overlays dead x_bf): 128-q blocks, 8 waves, 2 blocks/CU
  flash_attn<<<dim3(32, 16), dim3(512), 0, stream>>>(Qc, Qr, Kc, kr_bf, VTm, fr_bf, Om);
  // y = attn_out @ W_O
  tc_k<<<dim3(1024), blk, 0, stream>>>(wo, W);
  gemm_bf16<2><<<dim3(16, 32), blk, 0, stream>>>(Om, W, nullptr, nullptr, nullptr, out_y, nullptr,
                                                 nullptr, 4096, 2048, 2048);
}

// Round 9
// 374.095 us; speedup vs baseline: 1.0983x; 1.0120x over previous
//
#include <hip/hip_runtime.h>
#include <stdint.h>

typedef unsigned short u16;
typedef __attribute__((ext_vector_type(8))) short s16x8;
typedef __attribute__((ext_vector_type(4))) float f32x4;

#define B_   2
#define T_   2048
#define DM   2048
#define H_   16
#define HD_  128
#define R_   64
#define E_   192
// 1/sqrt(192) * log2(e): softmax in base-2 domain
#define SCALE2 0.104117542f

__device__ __forceinline__ u16 f2b(float f) {
  union { float f; uint32_t u; } x; x.f = f;
  uint32_t u = x.u;
  return (u16)((u + 0x7FFFu + ((u >> 16) & 1u)) >> 16);  // RNE
}
__device__ __forceinline__ float b2f(u16 h) {
  union { uint32_t u; float f; } x; x.u = ((uint32_t)h) << 16;
  return x.f;
}
// pack two f32 -> two bf16 (truncation; used only for P which is renormalized by row-sum)
__device__ __forceinline__ unsigned pk2(float a, float b) {
  union { float f; unsigned u; } A, B; A.f = a; B.f = b;
  return (B.u & 0xFFFF0000u) | (A.u >> 16);
}
// async global->LDS, 16B/lane; LDS dest = wave-uniform base + lane*16
__device__ __forceinline__ void ld_lds16(const void* g, void* l) {
  __builtin_amdgcn_global_load_lds((const __attribute__((address_space(1))) void*)g,
                                   (__attribute__((address_space(3))) void*)l,
                                   16, 0, 0);
}

// ---------- device helpers: conv + 64x64 transpose tile ----------
__device__ __forceinline__ void conv_dev(const float* __restrict__ in, u16* __restrict__ out, int i) {
  float4 v = *(const float4*)(in + (size_t)i * 4);
  ushort4 o;
  o.x = f2b(v.x); o.y = f2b(v.y); o.z = f2b(v.z); o.w = f2b(v.w);
  *(ushort4*)(out + (size_t)i * 4) = o;
}
__device__ __forceinline__ void tr64(const float* __restrict__ in, u16* __restrict__ out,
                                     int K, int N, int bx, int by) {
  __shared__ u16 t[64][65];
  int bn = bx * 64, bk = by * 64;
  int tid = threadIdx.x;
  int r0 = tid >> 4, c0 = (tid & 15) * 4;
#pragma unroll
  for (int rr = 0; rr < 64; rr += 16) {
    float4 v = *(const float4*)(in + (size_t)(bk + r0 + rr) * N + bn + c0);
    t[r0 + rr][c0 + 0] = f2b(v.x); t[r0 + rr][c0 + 1] = f2b(v.y);
    t[r0 + rr][c0 + 2] = f2b(v.z); t[r0 + rr][c0 + 3] = f2b(v.w);
  }
  __syncthreads();
#pragma unroll
  for (int rr = 0; rr < 64; rr += 16) {
    ushort4 v;
    v.x = t[c0 + 0][r0 + rr]; v.y = t[c0 + 1][r0 + rr];
    v.z = t[c0 + 2][r0 + rr]; v.w = t[c0 + 3][r0 + rr];
    *(ushort4*)(out + (size_t)(bn + r0 + rr) * K + bk + c0) = v;
  }
}

// ---------- TA: conv x, conv fr, transpose {W_DKV, W_KR, W_DQ} into gx arena.
// Merged mode (grid 10336): also transpose {W_UK, W_UV} -> UKUV and
// {W_UQ, W_QR} -> UQQR (weight-only, independent of everything downstream
// until kvq). Fallback mode launches only 9056 blocks (ext pointers unused).
__global__ __launch_bounds__(256)
void ta_k(const float* __restrict__ x, const float* __restrict__ fr,
          u16* __restrict__ x_bf, u16* __restrict__ fr_bf,
          const float* __restrict__ wdkv, const float* __restrict__ wkr,
          const float* __restrict__ wdq, u16* __restrict__ W,
          const float* __restrict__ wuk, const float* __restrict__ wuv,
          const float* __restrict__ wuq, const float* __restrict__ wqr,
          u16* __restrict__ UKUV, u16* __restrict__ UQQR) {
  int id = blockIdx.x;
  if (id < 8192)        conv_dev(x, x_bf, id * 256 + threadIdx.x);
  else if (id < 8256)   conv_dev(fr, fr_bf, (id - 8192) * 256 + threadIdx.x);
  else if (id < 8512) { int i = id - 8256; tr64(wdkv, W, 2048, 512, i & 7, i >> 3); }
  else if (id < 8544) { int i = id - 8512; tr64(wkr, W + 512 * 2048, 2048, 64, 0, i); }
  else if (id < 9056) { int i = id - 8544; tr64(wdq, W + 576 * 2048, 2048, 1024, i & 15, i >> 4); }
  else if (id < 9312) { int i = id - 9056; tr64(wuk, UKUV, 512, 2048, i & 31, i >> 5); }
  else if (id < 9568) { int i = id - 9312; tr64(wuv, UKUV + 2048 * 512, 512, 2048, i & 31, i >> 5); }
  else if (id < 10080){ int i = id - 9568; tr64(wuq, UQQR, 1024, 2048, i & 31, i >> 5); }
  else                { int i = id - 10080; tr64(wqr, UQQR + 2048 * 1024, 1024, 1024, i & 15, i >> 4); }
}
// ---------- TB1: {W_UK, W_UV} (fallback path only) ----------
__global__ __launch_bounds__(256)
void tb1_k(const float* __restrict__ wuk, const float* __restrict__ wuv, u16* __restrict__ W) {
  int id = blockIdx.x;
  if (id < 256) tr64(wuk, W, 512, 2048, id & 31, id >> 5);
  else { int i = id - 256; tr64(wuv, W + 2048 * 512, 512, 2048, i & 31, i >> 5); }
}
// ---------- TB2: {W_UQ, W_QR} (fallback path only) ----------
__global__ __launch_bounds__(256)
void tb2_k(const float* __restrict__ wuq, const float* __restrict__ wqr, u16* __restrict__ W) {
  int id = blockIdx.x;
  if (id < 512) tr64(wuq, W, 1024, 2048, id & 31, id >> 5);
  else { int i = id - 512; tr64(wqr, W + 2048 * 1024, 1024, 1024, i & 15, i >> 4); }
}
// ---------- TC: W_O (fallback path only; merged path folds this into kvq_k) ----------
__global__ __launch_bounds__(256)
void tc_k(const float* __restrict__ wo, u16* __restrict__ W) {
  tr64(wo, W, 2048, 2048, blockIdx.x & 31, blockIdx.x >> 5);
}

// ---------------- GEMM body: C(M,N) = A(M,K) * Bt(N,K)^T, bf16 in, fp32 acc ----------------
// BK=64 via two independent 32-wide LDS buffers (proven round-5 form; explicit
// dbuf prefetch measured exactly neutral in round 6).
// EPI 2: fp32 OF (y).
// EPI 4: n<2048 -> O0 bf16 (Kc); else V^T store to O1.
// EPI 5: n<2048 -> O0 (Qc); else O1 width 1024 (Qr raw).
// EPI 6: n<512 -> O0 (cKV) + OF fp32 (out_ckv); n<576 -> fused K-rope -> O1 bf16 (kr) + OF2 fp32;
//        n<1600 -> O2 width 1024 (cQ).
template <int EPI>
__device__ __forceinline__ void gemm_body(u16* Al, u16* Bl,
               const u16* __restrict__ A, const u16* __restrict__ Bt,
               u16* __restrict__ O0, u16* __restrict__ O1, u16* __restrict__ O2,
               float* __restrict__ OF, float* __restrict__ OF2,
               const u16* __restrict__ FR, int M, int N, int K, int bx, int by) {
  const int tid = threadIdx.x;
  const int ln = tid & 63, w = tid >> 6;
  const int quad = ln >> 4, l16 = ln & 15;
  const int wm = (w >> 1) * 64, wn = (w & 1) * 64;
  const int m0 = by * 128, n0 = bx * 128;

  f32x4 zz = {0.f, 0.f, 0.f, 0.f};
  f32x4 acc[4][4];
#pragma unroll
  for (int i = 0; i < 4; i++)
#pragma unroll
    for (int j = 0; j < 4; j++) acc[i][j] = zz;

  const u16* aG[2];
  const u16* bG[2];
  int ldsC[2];
#pragma unroll
  for (int r = 0; r < 2; r++) {
    int i = tid + r * 256;
    int row = i >> 2, cq = (i & 3) * 8;
    aG[r] = A + (size_t)(m0 + row) * K + cq;
    int rb = n0 + row;
    if (rb > N - 1) rb = N - 1;  // clamp for partial tiles (dup rows, cols discarded)
    bG[r] = Bt + (size_t)rb * K + cq;
    ldsC[r] = ((tid & ~63) + r * 256) * 8;  // wave-uniform chunk base (shorts)
  }

  for (int k = 0; k < K; k += 64) {
#pragma unroll
    for (int hh = 0; hh < 2; hh++)
#pragma unroll
      for (int r = 0; r < 2; r++) {
        ld_lds16(aG[r] + k + hh * 32, &Al[hh * 4096 + ldsC[r]]);
        ld_lds16(bG[r] + k + hh * 32, &Bl[hh * 4096 + ldsC[r]]);
      }
    __syncthreads();
#pragma unroll
    for (int hh = 0; hh < 2; hh++) {
      s16x8 af[4], bf[4];
#pragma unroll
      for (int f = 0; f < 4; f++)
        af[f] = *(const s16x8*)&Al[hh * 4096 + (wm + f * 16 + l16) * 32 + quad * 8];
#pragma unroll
      for (int f = 0; f < 4; f++)
        bf[f] = *(const s16x8*)&Bl[hh * 4096 + (wn + f * 16 + l16) * 32 + quad * 8];
#pragma unroll
      for (int i = 0; i < 4; i++)
#pragma unroll
        for (int j = 0; j < 4; j++)
          acc[i][j] = __builtin_amdgcn_mfma_f32_16x16x32_bf16(af[i], bf[j], acc[i][j], 0, 0, 0);
    }
    __syncthreads();
  }

#pragma unroll
  for (int fm = 0; fm < 4; fm++) {
#pragma unroll
    for (int fn = 0; fn < 4; fn++) {
      int n = n0 + wn + fn * 16 + l16;
      int mb = m0 + wm + fm * 16 + quad * 4;
      if (EPI == 2) {
        if (n < N) {
#pragma unroll
          for (int rg = 0; rg < 4; rg++) OF[(size_t)(mb + rg) * N + n] = acc[fm][fn][rg];
        }
      } else if (EPI == 4) {
        if (n < 2048) {
#pragma unroll
          for (int rg = 0; rg < 4; rg++) O0[(size_t)(mb + rg) * 2048 + n] = f2b(acc[fm][fn][rg]);
        } else {
          int hd = n - 2048, b = mb >> 11, t = mb & 2047;
          ushort4 v;
          v.x = f2b(acc[fm][fn][0]); v.y = f2b(acc[fm][fn][1]);
          v.z = f2b(acc[fm][fn][2]); v.w = f2b(acc[fm][fn][3]);
          *(ushort4*)(O1 + ((size_t)(b * 2048 + hd) * 2048 + t)) = v;
        }
      } else if (EPI == 5) {
        if (n < 2048) {
#pragma unroll
          for (int rg = 0; rg < 4; rg++) O0[(size_t)(mb + rg) * 2048 + n] = f2b(acc[fm][fn][rg]);
        } else {
#pragma unroll
          for (int rg = 0; rg < 4; rg++) O1[(size_t)(mb + rg) * 1024 + (n - 2048)] = f2b(acc[fm][fn][rg]);
        }
      } else {  // EPI 6
        if (n < 512) {
#pragma unroll
          for (int rg = 0; rg < 4; rg++) {
            float v = acc[fm][fn][rg];
            O0[(size_t)(mb + rg) * 512 + n] = f2b(v);
            OF[(size_t)(mb + rg) * 512 + n] = v;
          }
        } else if (n < 576) {
          // fused K-rope: adjacent lanes hold the (even,odd) pair
          int r = n - 512, r2 = r >> 1, odd = r & 1;
#pragma unroll
          for (int rg = 0; rg < 4; rg++) {
            float v = acc[fm][fn][rg];
            float p = __shfl_xor(v, 1);
            int t = mb + rg;
            float a = b2f(FR[(size_t)(t & 2047) * 32 + r2]);
            float sn, cs;
            __sincosf(a, &sn, &cs);
            float y = odd ? (p * sn + v * cs) : (v * cs - p * sn);
            O1[(size_t)t * 64 + r] = f2b(y);
            OF2[(size_t)t * 64 + r] = y;
          }
        } else if (n < 1600) {
#pragma unroll
          for (int rg = 0; rg < 4; rg++) O2[(size_t)(mb + rg) * 1024 + (n - 576)] = f2b(acc[fm][fn][rg]);
        }
      }
    }
  }
}

template <int EPI>
__global__ __launch_bounds__(256)
void gemm_bf16(const u16* __restrict__ A, const u16* __restrict__ Bt,
               u16* __restrict__ O0, u16* __restrict__ O1, u16* __restrict__ O2,
               float* __restrict__ OF, float* __restrict__ OF2,
               const u16* __restrict__ FR, int M, int N, int K) {
  __shared__ __align__(16) u16 Al[2 * 128 * 32];
  __shared__ __align__(16) u16 Bl[2 * 128 * 32];
  gemm_body<EPI>(Al, Bl, A, Bt, O0, O1, O2, OF, OF2, FR, M, N, K, blockIdx.x, blockIdx.y);
}

// ---------- merged gkv+gq+tc: 2816 blocks.
// gq (K=1024, longest) first, then gkv (K=512), then 1024 cheap W_O transpose
// blocks that fill the GEMM drain. W arena is free by now (gx completed before
// this launch) and g8 (its consumer) runs two launches later -> no hazard.
// Removes the separate tc_k launch from the flash->g8 critical path.
__global__ __launch_bounds__(256)
void kvq_k(const u16* __restrict__ cKV, const u16* __restrict__ UKUV,
           u16* __restrict__ Kc, u16* __restrict__ VT,
           const u16* __restrict__ cQ, const u16* __restrict__ UQQR,
           u16* __restrict__ Qc, u16* __restrict__ Qr,
           const float* __restrict__ wo, u16* __restrict__ W) {
  __shared__ __align__(16) u16 Al[2 * 128 * 32];
  __shared__ __align__(16) u16 Bl[2 * 128 * 32];
  int id = blockIdx.x;
  if (id < 768) {       // gq: 24 x 32 tiles of (4096, 3072), K=1024
    gemm_body<5>(Al, Bl, cQ, UQQR, Qc, Qr, nullptr, nullptr, nullptr, nullptr,
                 4096, 3072, 1024, id % 24, id / 24);
  } else if (id < 1792) {  // gkv: 32 x 32 tiles of (4096, 4096), K=512
    int j = id - 768;
    gemm_body<4>(Al, Bl, cKV, UKUV, Kc, VT, nullptr, nullptr, nullptr, nullptr,
                 4096, 4096, 512, j & 31, j >> 5);
  } else {              // tc: W_O transpose into the (now free) W arena
    int j = id - 1792;
    tr64(wo, W, 2048, 2048, j & 31, j >> 5);
  }
}

// ---------------- flash attention (S^T formulation, 64-key tiles, 128-q blocks) ----------------
// ROUND-5 FORM: round-7's balanced-y remap + setprio regressed 95->115 us
// (setprio starves prefetch-issuing waves in this 8-wave barrier-synced
// structure — m190 lockstep case; the remap can't beat the longest block's
// single-block-rate floor).
// grid (bh=32, tile=16): 512-thread blocks (8 waves), each covering 128 q-rows.
// K/V staging per key-tile is amortized over 8 waves; grid 512 = 2 blocks/CU.
// Longest tile at y=0 dispatches first; same-bh blocks keep id%8 => same XCD.
// Waves fully above a key-tile (k0 > qw+15) skip compute (barriers kept).
// P feeds PV DIRECTLY from registers: Vt key-columns are stored PERMUTED at
// staging time so the S^T output lane layout is already a valid PV A-fragment
// (Vt col c = 32*(key>>5) + ((key>>2)&3)*8 + ((key>>4)&1)*4 + (key&3)).
// launch_bounds (512,2): no VGPR clamp (round-2 lesson: forcing waves/EU
// causes accumulator spills); natural ~80 VGPR.
#define KT_S 200  // 64 keys x 192e (+pad): 100 dwords = 4 mod 32 -> 2-way reads (free)
#define VT_S 72   // 144 rows x 64 keys (+pad): 36 dwords
__global__ __launch_bounds__(512, 2)
void flash_attn(const u16* __restrict__ Qc, const u16* __restrict__ Qr,
                const u16* __restrict__ Kc, const u16* __restrict__ Kr,
                const u16* __restrict__ VT, const u16* __restrict__ fr,
                u16* __restrict__ O) {
  __shared__ __align__(16) u16 Kt[64 * KT_S];      // 25.6 KB [key][e]
  __shared__ __align__(16) u16 Vt[144 * VT_S];     // 20.7 KB [hd + 16 ones rows][perm key]

  const int tid = threadIdx.x;
  const int ln = tid & 63, w = tid >> 6;            // w = 0..7
  const int quad = ln >> 4, l16 = ln & 15;
  const int bh = blockIdx.x, b = bh >> 4, h = bh & 15;

  // ones rows 128..143 (row-sum trick); written once (perm-invariant: all 1.0)
  for (int i = tid; i < 1024; i += 512) Vt[(128 + (i >> 6)) * VT_S + (i & 63)] = 0x3F80;

  // staging maps (tile-invariant): K = 64 keys x 24 chunks, V = 128 rows x 8 chunks
  const u16* kBase[3]; int kStep[3], kLds[3];
#pragma unroll
  for (int r = 0; r < 3; r++) {
    int i = tid + r * 512;
    int key = i / 24, c = i - key * 24;
    kLds[r] = key * KT_S + c * 8;
    if (c < 16) { kBase[r] = Kc + ((size_t)(b * T_ + key) * DM + h * HD_ + c * 8); kStep[r] = 64 * DM; }
    else        { kBase[r] = Kr + ((size_t)(b * T_ + key) * R_ + (c - 16) * 8);    kStep[r] = 64 * R_; }
  }
  // V: each lane loads 8 consecutive keys (group c); they land as two 4-key
  // runs at the permuted columns colA and colA+8 (see perm above).
  const u16* vBase[2]; int vLds[2];
#pragma unroll
  for (int r = 0; r < 2; r++) {
    int i = tid + r * 512;
    int row = i >> 3, c = i & 7, c2 = c & 3;
    vLds[r] = row * VT_S + (c >> 2) * 32 + ((2 * c2) & 3) * 8 + (c2 >> 1) * 4;
    vBase[r] = VT + ((size_t)(bh * HD_ + row) * T_ + c * 8);
  }

  f32x4 zz = {0.f, 0.f, 0.f, 0.f};
  const int q0 = (15 - (int)blockIdx.y) * 128;   // y=0 dispatches first -> longest first
  const int qw = q0 + w * 16;

  // Q fragments (B-operand: n=l16 (q), k=quad*8+j (e)); rope fused for e>=128
  s16x8 qf[6];
  {
    int t = qw + l16;
    const u16* p = Qc + ((size_t)(b * T_ + t) * DM + h * HD_ + quad * 8);
#pragma unroll
    for (int f = 0; f < 4; f++) qf[f] = *(const s16x8*)(p + f * 32);
    const u16* pr = Qr + ((size_t)(b * T_ + t) * (H_ * R_) + h * R_ + quad * 8);
#pragma unroll
    for (int half = 0; half < 2; half++) {
      s16x8 v = *(const s16x8*)(pr + half * 32);
      s16x8 o2;
#pragma unroll
      for (int p2 = 0; p2 < 4; p2++) {
        float a = b2f(fr[t * 32 + half * 16 + quad * 4 + p2]);
        float sn, cs;
        __sincosf(a, &sn, &cs);
        float x0 = b2f((u16)v[2 * p2]), x1 = b2f((u16)v[2 * p2 + 1]);
        o2[2 * p2] = (short)f2b(x0 * cs - x1 * sn);
        o2[2 * p2 + 1] = (short)f2b(x0 * sn + x1 * cs);
      }
      qf[4 + half] = o2;
    }
  }

  f32x4 o[9];
#pragma unroll
  for (int f = 0; f < 9; f++) o[f] = zz;
  float mL = -1e30f;  // running max for q = qw + l16

  // prefetch tile k0=0
  const u16* pk[3]; const u16* pv[2];
  s16x8 kv[3], vv[2];
#pragma unroll
  for (int r = 0; r < 3; r++) { pk[r] = kBase[r]; kv[r] = *(const s16x8*)pk[r]; }
#pragma unroll
  for (int r = 0; r < 2; r++) { pv[r] = vBase[r]; vv[r] = *(const s16x8*)pv[r]; }

  const int nk = q0 + 128;
  for (int k0 = 0; k0 < nk; k0 += 64) {
    __syncthreads();  // previous tile fully consumed
#pragma unroll
    for (int r = 0; r < 3; r++) *(s16x8*)&Kt[kLds[r]] = kv[r];
#pragma unroll
    for (int r = 0; r < 2; r++) {
      union { s16x8 v; uint4 u; } V_; V_.v = vv[r];
      uint2 lo; lo.x = V_.u.x; lo.y = V_.u.y;
      uint2 hi; hi.x = V_.u.z; hi.y = V_.u.w;
      *(uint2*)&Vt[vLds[r]] = lo;
      *(uint2*)&Vt[vLds[r] + 8] = hi;
    }
    __syncthreads();  // staging visible
    if (k0 + 64 < nk) {
#pragma unroll
      for (int r = 0; r < 3; r++) { pk[r] += kStep[r]; kv[r] = *(const s16x8*)pk[r]; }
#pragma unroll
      for (int r = 0; r < 2; r++) { pv[r] += 64; vv[r] = *(const s16x8*)pv[r]; }
    }
    if (k0 > qw + 15) continue;  // tile fully above this wave's causal range

    // S^T = K * Q^T : A-frag = K rows (keys), B-frag = Q (regs)
    f32x4 s[4];
#pragma unroll
    for (int kg = 0; kg < 4; kg++) s[kg] = zz;
#pragma unroll
    for (int e = 0; e < 6; e++)
#pragma unroll
      for (int kg = 0; kg < 4; kg++) {
        s16x8 kf = *(const s16x8*)&Kt[(kg * 16 + l16) * KT_S + e * 32 + quad * 8];
        s[kg] = __builtin_amdgcn_mfma_f32_16x16x32_bf16(kf, qf[e], s[kg], 0, 0, 0);
      }
    // lane holds S^T[key = k0 + kg*16 + quad*4 + rg][q = qw + l16]
    const int q = qw + l16;
    float sv[16];
    if (k0 + 63 <= qw) {  // wave-uniform full tile: no mask needed
#pragma unroll
      for (int kg = 0; kg < 4; kg++)
#pragma unroll
        for (int rg = 0; rg < 4; rg++) sv[kg * 4 + rg] = s[kg][rg] * SCALE2;
    } else {
#pragma unroll
      for (int kg = 0; kg < 4; kg++)
#pragma unroll
        for (int rg = 0; rg < 4; rg++) {
          int key = k0 + kg * 16 + quad * 4 + rg;
          sv[kg * 4 + rg] = (key > q) ? -1e30f : s[kg][rg] * SCALE2;
        }
    }
    // tree max (short critical chain; compiler can fuse to v_max3)
    float mxa = fmaxf(fmaxf(sv[0], sv[1]), fmaxf(sv[2], sv[3]));
    float mxb = fmaxf(fmaxf(sv[4], sv[5]), fmaxf(sv[6], sv[7]));
    float mxc = fmaxf(fmaxf(sv[8], sv[9]), fmaxf(sv[10], sv[11]));
    float mxd = fmaxf(fmaxf(sv[12], sv[13]), fmaxf(sv[14], sv[15]));
    float mx = fmaxf(fmaxf(mxa, mxb), fmaxf(mxc, mxd));
    mx = fmaxf(mx, __shfl_xor(mx, 16));
    mx = fmaxf(mx, __shfl_xor(mx, 32));
    if (__any(mx > mL)) {  // new max somewhere in wave: rescale path
      float mn = fmaxf(mL, mx);
      float alpha = exp2f(mL - mn);
      mL = mn;
      float al[4];
#pragma unroll
      for (int rg = 0; rg < 4; rg++) al[rg] = __shfl(alpha, (ln & 48) | (quad * 4 + rg));
#pragma unroll
      for (int f = 0; f < 9; f++)
#pragma unroll
        for (int rg = 0; rg < 4; rg++) o[f][rg] *= al[rg];
    }
    float p[16];
#pragma unroll
    for (int j = 0; j < 16; j++) p[j] = exp2f(sv[j] - mL);
    // pack P in place: pw[0..3] IS the PV A-fragment for keys k0..k0+31
    // (matching Vt's permuted columns), pw[4..7] for keys k0+32..k0+63.
    // No LDS, no cross-lane ops.
    union { unsigned pw[8]; s16x8 pa[2]; } P_;
#pragma unroll
    for (int kg = 0; kg < 4; kg++) {
      P_.pw[kg * 2 + 0] = pk2(p[kg * 4 + 0], p[kg * 4 + 1]);
      P_.pw[kg * 2 + 1] = pk2(p[kg * 4 + 2], p[kg * 4 + 3]);
    }
    // PV: A = P (m=q=l16, k=perm key), B = V^T rows (f=8 -> ones rows = row sums)
#pragma unroll
    for (int f = 0; f < 9; f++) {
      s16x8 vb0 = *(const s16x8*)&Vt[(f * 16 + l16) * VT_S + quad * 8];
      o[f] = __builtin_amdgcn_mfma_f32_16x16x32_bf16(P_.pa[0], vb0, o[f], 0, 0, 0);
      s16x8 vb1 = *(const s16x8*)&Vt[(f * 16 + l16) * VT_S + 32 + quad * 8];
      o[f] = __builtin_amdgcn_mfma_f32_16x16x32_bf16(P_.pa[1], vb1, o[f], 0, 0, 0);
    }
  }

  float inv[4];
#pragma unroll
  for (int rg = 0; rg < 4; rg++) inv[rg] = 1.0f / o[8][rg];  // row-sum from ones rows
#pragma unroll
  for (int f = 0; f < 8; f++) {
#pragma unroll
    for (int rg = 0; rg < 4; rg++) {
      int qq = qw + quad * 4 + rg;
      O[(size_t)(b * T_ + qq) * DM + h * HD_ + f * 16 + l16] = f2b(o[f][rg] * inv[rg]);
    }
  }
}

// ---------------- launch ----------------
extern "C" void kernel_launch(void* const* d_in, const int* in_sizes, int n_in,
                              void* d_out, int out_size, void* d_ws, size_t ws_size,
                              hipStream_t stream) {
  const float* x    = (const float*)d_in[0];
  const float* fr   = (const float*)d_in[1];
  const float* wdkv = (const float*)d_in[2];
  const float* wuk  = (const float*)d_in[3];
  const float* wuv  = (const float*)d_in[4];
  const float* wkr  = (const float*)d_in[5];
  const float* wdq  = (const float*)d_in[6];
  const float* wuq  = (const float*)d_in[7];
  const float* wqr  = (const float*)d_in[8];
  const float* wo   = (const float*)d_in[9];
  u16* ws = (u16*)d_ws;

  const size_t M1 = 1048576;
  u16* x_bf  = ws;                 // 8M (dead after gx) -> Om overlays
  u16* Om    = ws;                 // 8M [flash..g8]
  u16* Kc    = ws + 8 * M1;        // 8M (b,t,h*hd)
  u16* VTm   = ws + 16 * M1;       // 8M (b,h*hd,t)
  u16* Qc    = ws + 24 * M1;       // 8M (b,t,h*hd)
  u16* Qr    = ws + 32 * M1;       // 4M (b,t,h,r) RAW (rope fused in flash)
  u16* W     = ws + 36 * M1;       // 4M transpose arena (gx weights, then W_O)
  u16* cKV   = ws + 40 * M1;       // 2M
  u16* cQ    = ws + 42 * M1;       // 4M
  u16* fr_bf = ws + 46 * M1;       // 65536
  u16* kr_bf = fr_bf + 65536;      // 262144
  u16* UKUV  = ws + 47 * M1;       // 2M  (merged mode only)
  u16* UQQR  = ws + 49 * M1;       // 3M  (merged mode only; ends at 52M)

  float* out_y   = (float*)d_out;              // (b,t,2048)
  float* out_ckv = (float*)d_out + 8388608;    // (b,t,512)
  float* out_kr  = (float*)d_out + 10485760;   // (b,t,64)
  (void)in_sizes; (void)n_in; (void)out_size;

  dim3 blk(256);
  const bool merged = ws_size >= (size_t)52 * M1 * 2;  // need 104 MiB of workspace

  if (merged) {
    // TA: conv x, conv fr, ALL input-side weight transposes
    ta_k<<<dim3(10336), blk, 0, stream>>>(x, fr, x_bf, fr_bf, wdkv, wkr, wdq, W,
                                          wuk, wuv, wuq, wqr, UKUV, UQQR);
    // gx: [cKV | K_r(rope) | cQ] = x @ [W_DKV | W_KR | W_DQ]
    gemm_bf16<6><<<dim3(13, 32), blk, 0, stream>>>(x_bf, W, cKV, kr_bf, cQ, out_ckv, out_kr, fr_bf,
                                                   4096, 1600, 2048);
    // merged gkv+gq+tc: 2816 blocks; W_O transpose fills the GEMM tail
    kvq_k<<<dim3(2816), blk, 0, stream>>>(cKV, UKUV, Kc, VTm, cQ, UQQR, Qc, Qr, wo, W);
  } else {
    // fallback: round-5 sequence (93 MB high-water)
    ta_k<<<dim3(9056), blk, 0, stream>>>(x, fr, x_bf, fr_bf, wdkv, wkr, wdq, W,
                                         wuk, wuv, wuq, wqr, UKUV, UQQR);
    gemm_bf16<6><<<dim3(13, 32), blk, 0, stream>>>(x_bf, W, cKV, kr_bf, cQ, out_ckv, out_kr, fr_bf,
                                                   4096, 1600, 2048);
    tb1_k<<<dim3(512), blk, 0, stream>>>(wuk, wuv, W);
    gemm_bf16<4><<<dim3(32, 32), blk, 0, stream>>>(cKV, W, Kc, VTm, nullptr, nullptr, nullptr,
                                                   nullptr, 4096, 4096, 512);
    tb2_k<<<dim3(768), blk, 0, stream>>>(wuq, wqr, W);
    gemm_bf16<5><<<dim3(24, 32), blk, 0, stream>>>(cQ, W, Qc, Qr, nullptr, nullptr, nullptr,
                                                   nullptr, 4096, 3072, 1024);
  }
  // attention (Om overlays dead x_bf): 128-q blocks, 8 waves, 2 blocks/CU
  flash_attn<<<dim3(32, 16), dim3(512), 0, stream>>>(Qc, Qr, Kc, kr_bf, VTm, fr_bf, Om);
  if (!merged) {
    tc_k<<<dim3(1024), blk, 0, stream>>>(wo, W);
  }
  // y = attn_out @ W_O
  gemm_bf16<2><<<dim3(16, 32), blk, 0, stream>>>(Om, W, nullptr, nullptr, nullptr, out_y, nullptr,
                                                 nullptr, 4096, 2048, 2048);
}

// Round 10
// 367.004 us; speedup vs baseline: 1.1195x; 1.0193x over previous
//
#include <hip/hip_runtime.h>
#include <stdint.h>

typedef unsigned short u16;
typedef __attribute__((ext_vector_type(8))) short s16x8;
typedef __attribute__((ext_vector_type(4))) float f32x4;

#define B_   2
#define T_   2048
#define DM   2048
#define H_   16
#define HD_  128
#define R_   64
#define E_   192
// 1/sqrt(192) * log2(e): softmax in base-2 domain
#define SCALE2 0.104117542f

__device__ __forceinline__ u16 f2b(float f) {
  union { float f; uint32_t u; } x; x.f = f;
  uint32_t u = x.u;
  return (u16)((u + 0x7FFFu + ((u >> 16) & 1u)) >> 16);  // RNE
}
__device__ __forceinline__ float b2f(u16 h) {
  union { uint32_t u; float f; } x; x.u = ((uint32_t)h) << 16;
  return x.f;
}
// pack two f32 -> two bf16 (truncation; used only for P which is renormalized by row-sum)
__device__ __forceinline__ unsigned pk2(float a, float b) {
  union { float f; unsigned u; } A, B; A.f = a; B.f = b;
  return (B.u & 0xFFFF0000u) | (A.u >> 16);
}
// pack two u16 into a uint (little-endian: a = low half)
__device__ __forceinline__ unsigned pku(u16 a, u16 b) {
  return (unsigned)a | ((unsigned)b << 16);
}
// async global->LDS, 16B/lane; LDS dest = wave-uniform base + lane*16
__device__ __forceinline__ void ld_lds16(const void* g, void* l) {
  __builtin_amdgcn_global_load_lds((const __attribute__((address_space(1))) void*)g,
                                   (__attribute__((address_space(3))) void*)l,
                                   16, 0, 0);
}

// ---------- device helpers: conv + 64x64 transpose tile ----------
__device__ __forceinline__ void conv_dev(const float* __restrict__ in, u16* __restrict__ out, int i) {
  float4 v = *(const float4*)(in + (size_t)i * 4);
  ushort4 o;
  o.x = f2b(v.x); o.y = f2b(v.y); o.z = f2b(v.z); o.w = f2b(v.w);
  *(ushort4*)(out + (size_t)i * 4) = o;
}
__device__ __forceinline__ void tr64(const float* __restrict__ in, u16* __restrict__ out,
                                     int K, int N, int bx, int by) {
  __shared__ u16 t[64][65];
  int bn = bx * 64, bk = by * 64;
  int tid = threadIdx.x;
  int r0 = tid >> 4, c0 = (tid & 15) * 4;
#pragma unroll
  for (int rr = 0; rr < 64; rr += 16) {
    float4 v = *(const float4*)(in + (size_t)(bk + r0 + rr) * N + bn + c0);
    t[r0 + rr][c0 + 0] = f2b(v.x); t[r0 + rr][c0 + 1] = f2b(v.y);
    t[r0 + rr][c0 + 2] = f2b(v.z); t[r0 + rr][c0 + 3] = f2b(v.w);
  }
  __syncthreads();
#pragma unroll
  for (int rr = 0; rr < 64; rr += 16) {
    ushort4 v;
    v.x = t[c0 + 0][r0 + rr]; v.y = t[c0 + 1][r0 + rr];
    v.z = t[c0 + 2][r0 + rr]; v.w = t[c0 + 3][r0 + rr];
    *(ushort4*)(out + (size_t)(bn + r0 + rr) * K + bk + c0) = v;
  }
}

// ---------- TA: conv x, conv fr, transpose {W_DKV, W_KR, W_DQ} into gx arena.
// Merged mode (grid 10336): also transpose {W_UK, W_UV} -> UKUV and
// {W_UQ, W_QR} -> UQQR. Fallback mode launches only 9056 blocks.
__global__ __launch_bounds__(256)
void ta_k(const float* __restrict__ x, const float* __restrict__ fr,
          u16* __restrict__ x_bf, u16* __restrict__ fr_bf,
          const float* __restrict__ wdkv, const float* __restrict__ wkr,
          const float* __restrict__ wdq, u16* __restrict__ W,
          const float* __restrict__ wuk, const float* __restrict__ wuv,
          const float* __restrict__ wuq, const float* __restrict__ wqr,
          u16* __restrict__ UKUV, u16* __restrict__ UQQR) {
  int id = blockIdx.x;
  if (id < 8192)        conv_dev(x, x_bf, id * 256 + threadIdx.x);
  else if (id < 8256)   conv_dev(fr, fr_bf, (id - 8192) * 256 + threadIdx.x);
  else if (id < 8512) { int i = id - 8256; tr64(wdkv, W, 2048, 512, i & 7, i >> 3); }
  else if (id < 8544) { int i = id - 8512; tr64(wkr, W + 512 * 2048, 2048, 64, 0, i); }
  else if (id < 9056) { int i = id - 8544; tr64(wdq, W + 576 * 2048, 2048, 1024, i & 15, i >> 4); }
  else if (id < 9312) { int i = id - 9056; tr64(wuk, UKUV, 512, 2048, i & 31, i >> 5); }
  else if (id < 9568) { int i = id - 9312; tr64(wuv, UKUV + 2048 * 512, 512, 2048, i & 31, i >> 5); }
  else if (id < 10080){ int i = id - 9568; tr64(wuq, UQQR, 1024, 2048, i & 31, i >> 5); }
  else                { int i = id - 10080; tr64(wqr, UQQR + 2048 * 1024, 1024, 1024, i & 15, i >> 4); }
}
// ---------- TB1: {W_UK, W_UV} (fallback path only) ----------
__global__ __launch_bounds__(256)
void tb1_k(const float* __restrict__ wuk, const float* __restrict__ wuv, u16* __restrict__ W) {
  int id = blockIdx.x;
  if (id < 256) tr64(wuk, W, 512, 2048, id & 31, id >> 5);
  else { int i = id - 256; tr64(wuv, W + 2048 * 512, 512, 2048, i & 31, i >> 5); }
}
// ---------- TB2: {W_UQ, W_QR} (fallback path only) ----------
__global__ __launch_bounds__(256)
void tb2_k(const float* __restrict__ wuq, const float* __restrict__ wqr, u16* __restrict__ W) {
  int id = blockIdx.x;
  if (id < 512) tr64(wuq, W, 1024, 2048, id & 31, id >> 5);
  else { int i = id - 512; tr64(wqr, W + 2048 * 1024, 1024, 1024, i & 15, i >> 4); }
}
// ---------- TC: W_O (fallback path only; merged path folds this into kvq_k) ----------
__global__ __launch_bounds__(256)
void tc_k(const float* __restrict__ wo, u16* __restrict__ W) {
  tr64(wo, W, 2048, 2048, blockIdx.x & 31, blockIdx.x >> 5);
}

// ---------------- GEMM body: C(M,N) = A(M,K) * Bt(N,K)^T, bf16 in, fp32 acc ----------------
// BK=64 via two independent 32-wide LDS buffers (proven round-5 form).
// EPI 2: fp32 OF (y).
// EPI 4: n<2048 -> O0 bf16 (Kc); else V^T SCATTER store to O1 (fallback only).
// EPI 5: n<2048 -> O0 (Qc); else O1 width 1024 (Qr raw).
// EPI 6: n<512 -> O0 (cKV) + OF fp32 (out_ckv); n<576 -> fused K-rope -> O1 bf16 (kr) + OF2 fp32;
//        n<1600 -> O2 width 1024 (cQ).
// EPI 7 (kvq only): n0<2048 -> O0 (Kc); else V^T via per-wave 64x64 LDS
//        transpose epilogue -> COALESCED 16B stores to O1. Requires Al..Al+16896
//        contiguous (kvq's single SH array); each wave uses patch Al + w*4224
//        = [64][66] u16, free after the K-loop's final barrier (no extra syncs).
template <int EPI>
__device__ __forceinline__ void gemm_body(u16* Al, u16* Bl,
               const u16* __restrict__ A, const u16* __restrict__ Bt,
               u16* __restrict__ O0, u16* __restrict__ O1, u16* __restrict__ O2,
               float* __restrict__ OF, float* __restrict__ OF2,
               const u16* __restrict__ FR, int M, int N, int K, int bx, int by) {
  const int tid = threadIdx.x;
  const int ln = tid & 63, w = tid >> 6;
  const int quad = ln >> 4, l16 = ln & 15;
  const int wm = (w >> 1) * 64, wn = (w & 1) * 64;
  const int m0 = by * 128, n0 = bx * 128;

  f32x4 zz = {0.f, 0.f, 0.f, 0.f};
  f32x4 acc[4][4];
#pragma unroll
  for (int i = 0; i < 4; i++)
#pragma unroll
    for (int j = 0; j < 4; j++) acc[i][j] = zz;

  const u16* aG[2];
  const u16* bG[2];
  int ldsC[2];
#pragma unroll
  for (int r = 0; r < 2; r++) {
    int i = tid + r * 256;
    int row = i >> 2, cq = (i & 3) * 8;
    aG[r] = A + (size_t)(m0 + row) * K + cq;
    int rb = n0 + row;
    if (rb > N - 1) rb = N - 1;  // clamp for partial tiles (dup rows, cols discarded)
    bG[r] = Bt + (size_t)rb * K + cq;
    ldsC[r] = ((tid & ~63) + r * 256) * 8;  // wave-uniform chunk base (shorts)
  }

  for (int k = 0; k < K; k += 64) {
#pragma unroll
    for (int hh = 0; hh < 2; hh++)
#pragma unroll
      for (int r = 0; r < 2; r++) {
        ld_lds16(aG[r] + k + hh * 32, &Al[hh * 4096 + ldsC[r]]);
        ld_lds16(bG[r] + k + hh * 32, &Bl[hh * 4096 + ldsC[r]]);
      }
    __syncthreads();
#pragma unroll
    for (int hh = 0; hh < 2; hh++) {
      s16x8 af[4], bf[4];
#pragma unroll
      for (int f = 0; f < 4; f++)
        af[f] = *(const s16x8*)&Al[hh * 4096 + (wm + f * 16 + l16) * 32 + quad * 8];
#pragma unroll
      for (int f = 0; f < 4; f++)
        bf[f] = *(const s16x8*)&Bl[hh * 4096 + (wn + f * 16 + l16) * 32 + quad * 8];
#pragma unroll
      for (int i = 0; i < 4; i++)
#pragma unroll
        for (int j = 0; j < 4; j++)
          acc[i][j] = __builtin_amdgcn_mfma_f32_16x16x32_bf16(af[i], bf[j], acc[i][j], 0, 0, 0);
    }
    __syncthreads();
  }

#pragma unroll
  for (int fm = 0; fm < 4; fm++) {
#pragma unroll
    for (int fn = 0; fn < 4; fn++) {
      int n = n0 + wn + fn * 16 + l16;
      int mb = m0 + wm + fm * 16 + quad * 4;
      if (EPI == 2) {
        if (n < N) {
#pragma unroll
          for (int rg = 0; rg < 4; rg++) OF[(size_t)(mb + rg) * N + n] = acc[fm][fn][rg];
        }
      } else if (EPI == 4) {
        if (n < 2048) {
#pragma unroll
          for (int rg = 0; rg < 4; rg++) O0[(size_t)(mb + rg) * 2048 + n] = f2b(acc[fm][fn][rg]);
        } else {
          int hd = n - 2048, b = mb >> 11, t = mb & 2047;
          ushort4 v;
          v.x = f2b(acc[fm][fn][0]); v.y = f2b(acc[fm][fn][1]);
          v.z = f2b(acc[fm][fn][2]); v.w = f2b(acc[fm][fn][3]);
          *(ushort4*)(O1 + ((size_t)(b * 2048 + hd) * 2048 + t)) = v;
        }
      } else if (EPI == 5) {
        if (n < 2048) {
#pragma unroll
          for (int rg = 0; rg < 4; rg++) O0[(size_t)(mb + rg) * 2048 + n] = f2b(acc[fm][fn][rg]);
        } else {
#pragma unroll
          for (int rg = 0; rg < 4; rg++) O1[(size_t)(mb + rg) * 1024 + (n - 2048)] = f2b(acc[fm][fn][rg]);
        }
      } else if (EPI == 7) {
        if (n0 < 2048) {
#pragma unroll
          for (int rg = 0; rg < 4; rg++) O0[(size_t)(mb + rg) * 2048 + n] = f2b(acc[fm][fn][rg]);
        } else {
          // write fragment TRANSPOSED into this wave's private LDS patch:
          // Lw[col][row], col = fn*16+l16 (hd-local), row = fm*16+quad*4+rg (t-local)
          u16* Lw = Al + w * 4224;  // [64][66]
          int cl = fn * 16 + l16, rb = fm * 16 + quad * 4;
          *(unsigned*)&Lw[cl * 66 + rb]     = pku(f2b(acc[fm][fn][0]), f2b(acc[fm][fn][1]));
          *(unsigned*)&Lw[cl * 66 + rb + 2] = pku(f2b(acc[fm][fn][2]), f2b(acc[fm][fn][3]));
        }
      } else {  // EPI 6
        if (n < 512) {
#pragma unroll
          for (int rg = 0; rg < 4; rg++) {
            float v = acc[fm][fn][rg];
            O0[(size_t)(mb + rg) * 512 + n] = f2b(v);
            OF[(size_t)(mb + rg) * 512 + n] = v;
          }
        } else if (n < 576) {
          // fused K-rope: adjacent lanes hold the (even,odd) pair
          int r = n - 512, r2 = r >> 1, odd = r & 1;
#pragma unroll
          for (int rg = 0; rg < 4; rg++) {
            float v = acc[fm][fn][rg];
            float p = __shfl_xor(v, 1);
            int t = mb + rg;
            float a = b2f(FR[(size_t)(t & 2047) * 32 + r2]);
            float sn, cs;
            __sincosf(a, &sn, &cs);
            float y = odd ? (p * sn + v * cs) : (v * cs - p * sn);
            O1[(size_t)t * 64 + r] = f2b(y);
            OF2[(size_t)t * 64 + r] = y;
          }
        } else if (n < 1600) {
#pragma unroll
          for (int rg = 0; rg < 4; rg++) O2[(size_t)(mb + rg) * 1024 + (n - 576)] = f2b(acc[fm][fn][rg]);
        }
      }
    }
  }
  if (EPI == 7) {
    if (n0 >= 2048) {
      // drain same-wave LDS writes, then read t-contiguous rows and store
      // coalesced 16B runs: VT[b][hd][t], 8 lanes cover 128 B of one hd row.
      __asm__ volatile("s_waitcnt lgkmcnt(0)" ::: "memory");
      u16* Lw = Al + w * 4224;
      int hd0 = n0 - 2048 + wn;
      int t0g = m0 + wm;
      int bb = t0g >> 11, tl = t0g & 2047;
#pragma unroll
      for (int i = 0; i < 8; i++) {
        int cl = (ln >> 3) + i * 8;
        int toff = (ln & 7) * 8;
        const u16* ls = &Lw[cl * 66 + toff];
        uint4 v;
        v.x = *(const unsigned*)(ls + 0); v.y = *(const unsigned*)(ls + 2);
        v.z = *(const unsigned*)(ls + 4); v.w = *(const unsigned*)(ls + 6);
        *(uint4*)&O1[((size_t)(bb * 2048 + hd0 + cl) * 2048) + tl + toff] = v;
      }
    }
  }
}

template <int EPI>
__global__ __launch_bounds__(256)
void gemm_bf16(const u16* __restrict__ A, const u16* __restrict__ Bt,
               u16* __restrict__ O0, u16* __restrict__ O1, u16* __restrict__ O2,
               float* __restrict__ OF, float* __restrict__ OF2,
               const u16* __restrict__ FR, int M, int N, int K) {
  __shared__ __align__(16) u16 Al[2 * 128 * 32];
  __shared__ __align__(16) u16 Bl[2 * 128 * 32];
  gemm_body<EPI>(Al, Bl, A, Bt, O0, O1, O2, OF, OF2, FR, M, N, K, blockIdx.x, blockIdx.y);
}

// ---------- merged gkv+gq+tc: 2816 blocks.
// gq (K=1024, longest) first, then gkv (K=512, EPI-7: coalesced V^T epilogue),
// then 1024 cheap W_O transpose blocks filling the GEMM drain. Single 33 KB
// SH array so the EPI-7 epilogue patches (4 x 4224 u16) are contiguous.
__global__ __launch_bounds__(256)
void kvq_k(const u16* __restrict__ cKV, const u16* __restrict__ UKUV,
           u16* __restrict__ Kc, u16* __restrict__ VT,
           const u16* __restrict__ cQ, const u16* __restrict__ UQQR,
           u16* __restrict__ Qc, u16* __restrict__ Qr,
           const float* __restrict__ wo, u16* __restrict__ W) {
  __shared__ __align__(16) u16 SH[16896];
  int id = blockIdx.x;
  if (id < 768) {       // gq: 24 x 32 tiles of (4096, 3072), K=1024
    gemm_body<5>(SH, SH + 8192, cQ, UQQR, Qc, Qr, nullptr, nullptr, nullptr, nullptr,
                 4096, 3072, 1024, id % 24, id / 24);
  } else if (id < 1792) {  // gkv: 32 x 32 tiles of (4096, 4096), K=512
    int j = id - 768;
    gemm_body<7>(SH, SH + 8192, cKV, UKUV, Kc, VT, nullptr, nullptr, nullptr, nullptr,
                 4096, 4096, 512, j & 31, j >> 5);
  } else {              // tc: W_O transpose into the (now free) W arena
    int j = id - 1792;
    tr64(wo, W, 2048, 2048, j & 31, j >> 5);
  }
}

// ---------------- flash attention (S^T formulation, 64-key tiles, 128-q blocks) ----------------
// grid (bh=32, tile=16): 512-thread blocks (8 waves), each covering 128 q-rows.
// K/V staging per key-tile is amortized over 8 waves; grid 512 = 2 blocks/CU.
// Longest tile at y=0 dispatches first; same-bh blocks keep id%8 => same XCD.
// Waves fully above a key-tile (k0 > qw+15) skip compute (barriers kept).
// T13 defer-rescale: skip the alpha/4-shfl/36-mult rescale while the tile max
// grows by <= 8 (base-2); P <= 2^8 is exact under the ones-row renormalization
// (scale cancels in the final division; bf16 precision is scale-invariant).
// P feeds PV DIRECTLY from registers: Vt key-columns are stored PERMUTED at
// staging time so the S^T output lane layout is already a valid PV A-fragment
// (Vt col c = 32*(key>>5) + ((key>>2)&3)*8 + ((key>>4)&1)*4 + (key&3)).
// launch_bounds (512,2): no VGPR clamp (round-2 lesson); natural ~80 VGPR.
#define KT_S 200  // 64 keys x 192e (+pad): 100 dwords = 4 mod 32 -> 2-way reads (free)
#define VT_S 72   // 144 rows x 64 keys (+pad): 36 dwords
__global__ __launch_bounds__(512, 2)
void flash_attn(const u16* __restrict__ Qc, const u16* __restrict__ Qr,
                const u16* __restrict__ Kc, const u16* __restrict__ Kr,
                const u16* __restrict__ VT, const u16* __restrict__ fr,
                u16* __restrict__ O) {
  __shared__ __align__(16) u16 Kt[64 * KT_S];      // 25.6 KB [key][e]
  __shared__ __align__(16) u16 Vt[144 * VT_S];     // 20.7 KB [hd + 16 ones rows][perm key]

  const int tid = threadIdx.x;
  const int ln = tid & 63, w = tid >> 6;            // w = 0..7
  const int quad = ln >> 4, l16 = ln & 15;
  const int bh = blockIdx.x, b = bh >> 4, h = bh & 15;

  // ones rows 128..143 (row-sum trick); written once (perm-invariant: all 1.0)
  for (int i = tid; i < 1024; i += 512) Vt[(128 + (i >> 6)) * VT_S + (i & 63)] = 0x3F80;

  // staging maps (tile-invariant): K = 64 keys x 24 chunks, V = 128 rows x 8 chunks
  const u16* kBase[3]; int kStep[3], kLds[3];
#pragma unroll
  for (int r = 0; r < 3; r++) {
    int i = tid + r * 512;
    int key = i / 24, c = i - key * 24;
    kLds[r] = key * KT_S + c * 8;
    if (c < 16) { kBase[r] = Kc + ((size_t)(b * T_ + key) * DM + h * HD_ + c * 8); kStep[r] = 64 * DM; }
    else        { kBase[r] = Kr + ((size_t)(b * T_ + key) * R_ + (c - 16) * 8);    kStep[r] = 64 * R_; }
  }
  // V: each lane loads 8 consecutive keys (group c); they land as two 4-key
  // runs at the permuted columns colA and colA+8 (see perm above).
  const u16* vBase[2]; int vLds[2];
#pragma unroll
  for (int r = 0; r < 2; r++) {
    int i = tid + r * 512;
    int row = i >> 3, c = i & 7, c2 = c & 3;
    vLds[r] = row * VT_S + (c >> 2) * 32 + ((2 * c2) & 3) * 8 + (c2 >> 1) * 4;
    vBase[r] = VT + ((size_t)(bh * HD_ + row) * T_ + c * 8);
  }

  f32x4 zz = {0.f, 0.f, 0.f, 0.f};
  const int q0 = (15 - (int)blockIdx.y) * 128;   // y=0 dispatches first -> longest first
  const int qw = q0 + w * 16;

  // Q fragments (B-operand: n=l16 (q), k=quad*8+j (e)); rope fused for e>=128
  s16x8 qf[6];
  {
    int t = qw + l16;
    const u16* p = Qc + ((size_t)(b * T_ + t) * DM + h * HD_ + quad * 8);
#pragma unroll
    for (int f = 0; f < 4; f++) qf[f] = *(const s16x8*)(p + f * 32);
    const u16* pr = Qr + ((size_t)(b * T_ + t) * (H_ * R_) + h * R_ + quad * 8);
#pragma unroll
    for (int half = 0; half < 2; half++) {
      s16x8 v = *(const s16x8*)(pr + half * 32);
      s16x8 o2;
#pragma unroll
      for (int p2 = 0; p2 < 4; p2++) {
        float a = b2f(fr[t * 32 + half * 16 + quad * 4 + p2]);
        float sn, cs;
        __sincosf(a, &sn, &cs);
        float x0 = b2f((u16)v[2 * p2]), x1 = b2f((u16)v[2 * p2 + 1]);
        o2[2 * p2] = (short)f2b(x0 * cs - x1 * sn);
        o2[2 * p2 + 1] = (short)f2b(x0 * sn + x1 * cs);
      }
      qf[4 + half] = o2;
    }
  }

  f32x4 o[9];
#pragma unroll
  for (int f = 0; f < 9; f++) o[f] = zz;
  float mL = -1e30f;  // running max for q = qw + l16

  // prefetch tile k0=0
  const u16* pk[3]; const u16* pv[2];
  s16x8 kv[3], vv[2];
#pragma unroll
  for (int r = 0; r < 3; r++) { pk[r] = kBase[r]; kv[r] = *(const s16x8*)pk[r]; }
#pragma unroll
  for (int r = 0; r < 2; r++) { pv[r] = vBase[r]; vv[r] = *(const s16x8*)pv[r]; }

  const int nk = q0 + 128;
  for (int k0 = 0; k0 < nk; k0 += 64) {
    __syncthreads();  // previous tile fully consumed
#pragma unroll
    for (int r = 0; r < 3; r++) *(s16x8*)&Kt[kLds[r]] = kv[r];
#pragma unroll
    for (int r = 0; r < 2; r++) {
      union { s16x8 v; uint4 u; } V_; V_.v = vv[r];
      uint2 lo; lo.x = V_.u.x; lo.y = V_.u.y;
      uint2 hi; hi.x = V_.u.z; hi.y = V_.u.w;
      *(uint2*)&Vt[vLds[r]] = lo;
      *(uint2*)&Vt[vLds[r] + 8] = hi;
    }
    __syncthreads();  // staging visible
    if (k0 + 64 < nk) {
#pragma unroll
      for (int r = 0; r < 3; r++) { pk[r] += kStep[r]; kv[r] = *(const s16x8*)pk[r]; }
#pragma unroll
      for (int r = 0; r < 2; r++) { pv[r] += 64; vv[r] = *(const s16x8*)pv[r]; }
    }
    if (k0 > qw + 15) continue;  // tile fully above this wave's causal range

    // S^T = K * Q^T : A-frag = K rows (keys), B-frag = Q (regs)
    f32x4 s[4];
#pragma unroll
    for (int kg = 0; kg < 4; kg++) s[kg] = zz;
#pragma unroll
    for (int e = 0; e < 6; e++)
#pragma unroll
      for (int kg = 0; kg < 4; kg++) {
        s16x8 kf = *(const s16x8*)&Kt[(kg * 16 + l16) * KT_S + e * 32 + quad * 8];
        s[kg] = __builtin_amdgcn_mfma_f32_16x16x32_bf16(kf, qf[e], s[kg], 0, 0, 0);
      }
    // lane holds S^T[key = k0 + kg*16 + quad*4 + rg][q = qw + l16]
    const int q = qw + l16;
    float sv[16];
    if (k0 + 63 <= qw) {  // wave-uniform full tile: no mask needed
#pragma unroll
      for (int kg = 0; kg < 4; kg++)
#pragma unroll
        for (int rg = 0; rg < 4; rg++) sv[kg * 4 + rg] = s[kg][rg] * SCALE2;
    } else {
#pragma unroll
      for (int kg = 0; kg < 4; kg++)
#pragma unroll
        for (int rg = 0; rg < 4; rg++) {
          int key = k0 + kg * 16 + quad * 4 + rg;
          sv[kg * 4 + rg] = (key > q) ? -1e30f : s[kg][rg] * SCALE2;
        }
    }
    // tree max (short critical chain; compiler can fuse to v_max3)
    float mxa = fmaxf(fmaxf(sv[0], sv[1]), fmaxf(sv[2], sv[3]));
    float mxb = fmaxf(fmaxf(sv[4], sv[5]), fmaxf(sv[6], sv[7]));
    float mxc = fmaxf(fmaxf(sv[8], sv[9]), fmaxf(sv[10], sv[11]));
    float mxd = fmaxf(fmaxf(sv[12], sv[13]), fmaxf(sv[14], sv[15]));
    float mx = fmaxf(fmaxf(mxa, mxb), fmaxf(mxc, mxd));
    mx = fmaxf(mx, __shfl_xor(mx, 16));
    mx = fmaxf(mx, __shfl_xor(mx, 32));
    if (__any(mx > mL + 8.0f)) {  // T13: rescale only on big max jumps
      float mn = fmaxf(mL, mx);
      float alpha = exp2f(mL - mn);
      mL = mn;
      float al[4];
#pragma unroll
      for (int rg = 0; rg < 4; rg++) al[rg] = __shfl(alpha, (ln & 48) | (quad * 4 + rg));
#pragma unroll
      for (int f = 0; f < 9; f++)
#pragma unroll
        for (int rg = 0; rg < 4; rg++) o[f][rg] *= al[rg];
    }
    float p[16];
#pragma unroll
    for (int j = 0; j < 16; j++) p[j] = exp2f(sv[j] - mL);
    // pack P in place: pw[0..3] IS the PV A-fragment for keys k0..k0+31
    // (matching Vt's permuted columns), pw[4..7] for keys k0+32..k0+63.
    // No LDS, no cross-lane ops.
    union { unsigned pw[8]; s16x8 pa[2]; } P_;
#pragma unroll
    for (int kg = 0; kg < 4; kg++) {
      P_.pw[kg * 2 + 0] = pk2(p[kg * 4 + 0], p[kg * 4 + 1]);
      P_.pw[kg * 2 + 1] = pk2(p[kg * 4 + 2], p[kg * 4 + 3]);
    }
    // PV: A = P (m=q=l16, k=perm key), B = V^T rows (f=8 -> ones rows = row sums)
#pragma unroll
    for (int f = 0; f < 9; f++) {
      s16x8 vb0 = *(const s16x8*)&Vt[(f * 16 + l16) * VT_S + quad * 8];
      o[f] = __builtin_amdgcn_mfma_f32_16x16x32_bf16(P_.pa[0], vb0, o[f], 0, 0, 0);
      s16x8 vb1 = *(const s16x8*)&Vt[(f * 16 + l16) * VT_S + 32 + quad * 8];
      o[f] = __builtin_amdgcn_mfma_f32_16x16x32_bf16(P_.pa[1], vb1, o[f], 0, 0, 0);
    }
  }

  float inv[4];
#pragma unroll
  for (int rg = 0; rg < 4; rg++) inv[rg] = 1.0f / o[8][rg];  // row-sum from ones rows
#pragma unroll
  for (int f = 0; f < 8; f++) {
#pragma unroll
    for (int rg = 0; rg < 4; rg++) {
      int qq = qw + quad * 4 + rg;
      O[(size_t)(b * T_ + qq) * DM + h * HD_ + f * 16 + l16] = f2b(o[f][rg] * inv[rg]);
    }
  }
}

// ---------------- launch ----------------
extern "C" void kernel_launch(void* const* d_in, const int* in_sizes, int n_in,
                              void* d_out, int out_size, void* d_ws, size_t ws_size,
                              hipStream_t stream) {
  const float* x    = (const float*)d_in[0];
  const float* fr   = (const float*)d_in[1];
  const float* wdkv = (const float*)d_in[2];
  const float* wuk  = (const float*)d_in[3];
  const float* wuv  = (const float*)d_in[4];
  const float* wkr  = (const float*)d_in[5];
  const float* wdq  = (const float*)d_in[6];
  const float* wuq  = (const float*)d_in[7];
  const float* wqr  = (const float*)d_in[8];
  const float* wo   = (const float*)d_in[9];
  u16* ws = (u16*)d_ws;

  const size_t M1 = 1048576;
  u16* x_bf  = ws;                 // 8M (dead after gx) -> Om overlays
  u16* Om    = ws;                 // 8M [flash..g8]
  u16* Kc    = ws + 8 * M1;        // 8M (b,t,h*hd)
  u16* VTm   = ws + 16 * M1;       // 8M (b,h*hd,t)
  u16* Qc    = ws + 24 * M1;       // 8M (b,t,h*hd)
  u16* Qr    = ws + 32 * M1;       // 4M (b,t,h,r) RAW (rope fused in flash)
  u16* W     = ws + 36 * M1;       // 4M transpose arena (gx weights, then W_O)
  u16* cKV   = ws + 40 * M1;       // 2M
  u16* cQ    = ws + 42 * M1;       // 4M
  u16* fr_bf = ws + 46 * M1;       // 65536
  u16* kr_bf = fr_bf + 65536;      // 262144
  u16* UKUV  = ws + 47 * M1;       // 2M  (merged mode only)
  u16* UQQR  = ws + 49 * M1;       // 3M  (merged mode only; ends at 52M)

  float* out_y   = (float*)d_out;              // (b,t,2048)
  float* out_ckv = (float*)d_out + 8388608;    // (b,t,512)
  float* out_kr  = (float*)d_out + 10485760;   // (b,t,64)
  (void)in_sizes; (void)n_in; (void)out_size;

  dim3 blk(256);
  const bool merged = ws_size >= (size_t)52 * M1 * 2;  // need 104 MiB of workspace

  if (merged) {
    // TA: conv x, conv fr, ALL input-side weight transposes
    ta_k<<<dim3(10336), blk, 0, stream>>>(x, fr, x_bf, fr_bf, wdkv, wkr, wdq, W,
                                          wuk, wuv, wuq, wqr, UKUV, UQQR);
    // gx: [cKV | K_r(rope) | cQ] = x @ [W_DKV | W_KR | W_DQ]
    gemm_bf16<6><<<dim3(13, 32), blk, 0, stream>>>(x_bf, W, cKV, kr_bf, cQ, out_ckv, out_kr, fr_bf,
                                                   4096, 1600, 2048);
    // merged gkv+gq+tc: 2816 blocks; W_O transpose fills the GEMM tail
    kvq_k<<<dim3(2816), blk, 0, stream>>>(cKV, UKUV, Kc, VTm, cQ, UQQR, Qc, Qr, wo, W);
  } else {
    // fallback: round-5 sequence (93 MB high-water)
    ta_k<<<dim3(9056), blk, 0, stream>>>(x, fr, x_bf, fr_bf, wdkv, wkr, wdq, W,
                                         wuk, wuv, wuq, wqr, UKUV, UQQR);
    gemm_bf16<6><<<dim3(13, 32), blk, 0, stream>>>(x_bf, W, cKV, kr_bf, cQ, out_ckv, out_kr, fr_bf,
                                                   4096, 1600, 2048);
    tb1_k<<<dim3(512), blk, 0, stream>>>(wuk, wuv, W);
    gemm_bf16<4><<<dim3(32, 32), blk, 0, stream>>>(cKV, W, Kc, VTm, nullptr, nullptr, nullptr,
                                                   nullptr, 4096, 4096, 512);
    tb2_k<<<dim3(768), blk, 0, stream>>>(wuq, wqr, W);
    gemm_bf16<5><<<dim3(24, 32), blk, 0, stream>>>(cQ, W, Qc, Qr, nullptr, nullptr, nullptr,
                                                   nullptr, 4096, 3072, 1024);
  }
  // attention (Om overlays dead x_bf): 128-q blocks, 8 waves, 2 blocks/CU
  flash_attn<<<dim3(32, 16), dim3(512), 0, stream>>>(Qc, Qr, Kc, kr_bf, VTm, fr_bf, Om);
  if (!merged) {
    tc_k<<<dim3(1024), blk, 0, stream>>>(wo, W);
  }
  // y = attn_out @ W_O
  gemm_bf16<2><<<dim3(16, 32), blk, 0, stream>>>(Om, W, nullptr, nullptr, nullptr, out_y, nullptr,
                                                 nullptr, 4096, 2048, 2048);
}